// Round 3
// baseline (1079.712 us; speedup 1.0000x reference)
//
#include <hip/hip_runtime.h>
#include <math.h>

#define BATCH 16384
#define B6 (BATCH*6)
#define DT 0.01f

__device__ __constant__ float c_LOWER[6]  = {-6.28f,-6.28f,-3.14f,-6.28f,-6.28f,-6.28f};
__device__ __constant__ float c_UPPER[6]  = { 6.28f, 6.28f, 3.14f, 6.28f, 6.28f, 6.28f};
__device__ __constant__ float c_EFFORT[6] = {150.0f,150.0f,150.0f,28.0f,28.0f,28.0f};
__device__ __constant__ int   c_ROWOFF[6] = {0,1,3,6,10,15};

__device__ __forceinline__ float sp_f(float z){ return fmaxf(z,0.0f) + log1pf(expf(-fabsf(z))); }
__device__ __forceinline__ float sig_f(float z){ return 1.0f/(1.0f+expf(-z)); }

__device__ __forceinline__ float4 f4all(float v){ return make_float4(v,v,v,v); }
__device__ __forceinline__ void fma4(float4& acc, float w, float4 a){
  acc.x=fmaf(w,a.x,acc.x); acc.y=fmaf(w,a.y,acc.y); acc.z=fmaf(w,a.z,acc.z); acc.w=fmaf(w,a.w,acc.w);
}
__device__ __forceinline__ float4 mul4(float4 a, float4 b){
  return make_float4(a.x*b.x, a.y*b.y, a.z*b.z, a.w*b.w);
}
__device__ __forceinline__ float4 sp4(float4 z){
  return make_float4(sp_f(z.x),sp_f(z.y),sp_f(z.z),sp_f(z.w));
}
__device__ __forceinline__ float4 sig4(float4 z){
  return make_float4(sig_f(z.x),sig_f(z.y),sig_f(z.z),sig_f(z.w));
}

// XOR-swizzled LDS accessors for [N][16] activation arrays.
// Element (n, s) chunk cc = s>>2 stored at physical chunk cc ^ ((n>>1)&3).
// -> column-chunk writes by 64 lanes (rows = lane, lane+64) cover all 8
//    bank-quads = conflict-free; chunk reads are single-address broadcasts.
__device__ __forceinline__ float4* chunkp(float (*arr)[16], int n, int cc){
  return reinterpret_cast<float4*>(&arr[n][4*(cc ^ ((n>>1)&3))]);
}
__device__ __forceinline__ const float4* chunkc(const float (*arr)[16], int n, int cc){
  return reinterpret_cast<const float4*>(&arr[n][4*(cc ^ ((n>>1)&3))]);
}
__device__ __forceinline__ float& el(float (*arr)[16], int n, int s){
  return arr[n][4*((s>>2) ^ ((n>>1)&3)) + (s&3)];
}

// 2 rows (ng2, ng2+64) x 4 samples GEMV tile. Wp layout: [NI][128] with
// row pair (k, k+64) packed at (2k, 2k+1) -> one float2 load per i.
template<int NI>
__device__ __forceinline__ void gemv2(const float* __restrict__ Wp,
                                      const float (*__restrict__ src)[16],
                                      int ng2, int sg, float4& a0, float4& a1){
  #pragma unroll 4
  for (int i=0;i<NI;i++){
    float2 w = reinterpret_cast<const float2*>(Wp + i*128)[ng2];
    float4 a = *chunkc(src, i, sg);
    fma4(a0, w.x, a);
    fma4(a1, w.y, a);
  }
}

// ---------------- init: transpose+pack weights, zero viol ----------------
__global__ void __launch_bounds__(256) k_init(
    const float* __restrict__ W1L, const float* __restrict__ W2L,
    const float* __restrict__ W1V, const float* __restrict__ W2V,
    const float* __restrict__ W3L,
    float* __restrict__ W1LTp, float* __restrict__ W2LTp,
    float* __restrict__ W1VTp, float* __restrict__ W2VTp,
    float* __restrict__ W2Vp,  float* __restrict__ W3LT, int* __restrict__ viol)
{
  int t = blockIdx.x*256 + threadIdx.x;
  if (t < 4) viol[t] = 0;
  if (t < 1536){
    int i = t/128, c = t%128, k = (c>>1) + 64*(c&1);
    W1LTp[t] = W1L[k*12+i]; W1VTp[t] = W1V[k*12+i];
  }
  if (t < 2688){ int i = t/21, o = t%21; W3LT[t] = W3L[o*128+i]; }
  if (t < 16384){
    int i = t/128, c = t%128, k = (c>>1) + 64*(c&1);
    W2LTp[t] = W2L[k*128+i];
    W2VTp[t] = W2V[k*128+i];
    W2Vp[t]  = W2V[i*128+k];
  }
}

// ---------------- per-stage state + batch viol reduction ----------------
__global__ void __launch_bounds__(256) k_pre(int stage,
    const float* __restrict__ obs, const float* __restrict__ kqd,
    float* __restrict__ q_cur, float* __restrict__ qd_cur, int* __restrict__ viol)
{
  int b = blockIdx.x*256 + threadIdx.x;
  if (b >= BATCH) return;
  const float* o = obs + b*12;
  unsigned mask = 0;
  #pragma unroll
  for (int i=0;i<6;i++){
    float q0 = o[i], qd0 = o[6+i];
    float q, qd;
    if (stage == 0){ q=q0; qd=qd0; }
    else if (stage == 1){
      q  = q0 + 0.5f*DT*qd0;
      qd = qd0 + 0.5f*DT*kqd[b*6+i];
    } else if (stage == 2){
      q  = q0 + 0.5f*DT*qd0 + 0.25f*DT*DT*kqd[b*6+i];
      qd = qd0 + 0.5f*DT*kqd[B6 + b*6+i];
    } else {
      q  = q0 + DT*qd0 + 0.5f*DT*DT*kqd[B6 + b*6+i];
      qd = qd0 + DT*kqd[2*B6 + b*6+i];
    }
    q_cur[b*6+i]=q; qd_cur[b*6+i]=qd;
    float lo = c_LOWER[i]+0.1f, up = c_UPPER[i]-0.1f;
    if (q <= lo || q >= up) mask |= (1u<<i);
  }
  unsigned wm = 0;
  #pragma unroll
  for (int i=0;i<6;i++) if (__ballot((int)((mask>>i)&1u))) wm |= (1u<<i);
  if ((threadIdx.x & 63)==0 && wm) atomicOr(viol + stage, (int)wm);
}

// ---------------- heavy per-stage accel ----------------
// 16 samples/block, 256 threads (4 waves). Wave = one 4-sample chunk
// (sg = tid>>6, wave-uniform -> all LDS gemv reads are broadcasts).
// Thread = rows {ng2, ng2+64} x 4 samples; sigmoid tiles in registers.
__global__ void __launch_bounds__(256, 4) k_accel(
    const float* __restrict__ q_cur, const float* __restrict__ qd_cur,
    const float* __restrict__ action,
    const float* __restrict__ W1LTp, const float* __restrict__ b1L,
    const float* __restrict__ W2LTp, const float* __restrict__ b2L,
    const float* __restrict__ W3LT,  const float* __restrict__ b3L,
    const float* __restrict__ W1VTp, const float* __restrict__ b1V,
    const float* __restrict__ W2VTp, const float* __restrict__ b2V,
    const float* __restrict__ W2Vp,  const float* __restrict__ W1V,
    const float* __restrict__ W3V,
    const int* __restrict__ viol_stage,
    float* __restrict__ kqd_out)
{
  __shared__ alignas(16) float sh_t[12][16];
  __shared__ alignas(16) float sh_A[128][16];
  __shared__ alignas(16) float sh_B[128][16];
  __shared__ alignas(16) float sh_y[21][16];
  __shared__ alignas(16) float sh_dy[21][16];
  __shared__ float sh_qd[6][16], sh_tau[6][16], sh_f[6][16];
  __shared__ float sh_c[6][16], sh_grav[6][16], sh_v[6][16];

  const int tid = threadIdx.x;
  const int ng2 = tid & 63;
  const int sg  = tid >> 6;      // wave index == sample-chunk index
  const int s0  = blockIdx.x * 16;
  const int vm  = *viol_stage;

  // ---- load tile, trig features, tau, constraint force
  if (tid < 96){
    int s = tid & 15, i = tid >> 4;
    float q  = q_cur [(s0+s)*6 + i];
    float qd = qd_cur[(s0+s)*6 + i];
    sh_qd[i][s]=qd;
    sh_tau[i][s] = action[(s0+s)*6+i] * c_EFFORT[i];
    el(sh_t, 2*i,   s) = cosf(q);
    el(sh_t, 2*i+1, s) = sinf(q);
    float lo = c_LOWER[i]+0.1f, up = c_UPPER[i]-0.1f;
    float barrier = -5.0f*(1.0f/(q-lo) - 1.0f/(up-q));
    float clip = (q<=lo)? c_EFFORT[i] : ((q>=up)? -c_EFFORT[i] : 0.0f);
    sh_f[i][s] = ((vm>>i)&1) ? clip : barrier;
    sh_c[i][s] = 0.0f;
  }
  __syncthreads();

  float4 s1t[2], s2t[2];

  // ---- L-net layer 1
  {
    float4 z0 = f4all(b1L[ng2]), z1 = f4all(b1L[ng2+64]);
    gemv2<12>(W1LTp, sh_t, ng2, sg, z0, z1);
    *chunkp(sh_A, ng2,    sg) = sp4(z0);  s1t[0] = sig4(z0);
    *chunkp(sh_A, ng2+64, sg) = sp4(z1);  s1t[1] = sig4(z1);
  }
  __syncthreads();

  // ---- L-net layer 2
  {
    float4 z0 = f4all(b2L[ng2]), z1 = f4all(b2L[ng2+64]);
    gemv2<128>(W2LTp, sh_A, ng2, sg, z0, z1);
    *chunkp(sh_B, ng2,    sg) = sp4(z0);  s2t[0] = sig4(z0);
    *chunkp(sh_B, ng2+64, sg) = sp4(z1);  s2t[1] = sig4(z1);
  }
  __syncthreads();

  // ---- L-net layer 3 (21 outputs): lane ng2<21 owns row ng2
  float4 s3t = f4all(0.f);
  if (ng2 < 21){
    float4 acc = f4all(b3L[ng2]);
    #pragma unroll 4
    for (int i=0;i<128;i++){
      float w = W3LT[i*21+ng2];
      fma4(acc, w, *chunkc(sh_B, i, sg));
    }
    *chunkp(sh_y, ng2, sg) = sp4(acc);
    s3t = sig4(acc);
  }
  __syncthreads();

  // ---- v = L^T qdot
  if (tid < 96){
    int s = tid & 15, jj = tid >> 4;
    float acc = 0.f;
    for (int i=jj;i<6;i++) acc = fmaf(el(sh_y, c_ROWOFF[i]+jj, s), sh_qd[i][s], acc);
    sh_v[jj][s] = acc;
  }

  // ---- tangent loop over g: dM/dq_g, accumulate Coriolis c
  for (int g=0; g<6; ++g){
    __syncthreads();
    // dh1 = s1 * (cos*W1[:,2g+1] - sin*W1[:,2g])  -> sh_A
    {
      float2 w0 = reinterpret_cast<const float2*>(W1LTp + (2*g)*128)[ng2];
      float2 w1 = reinterpret_cast<const float2*>(W1LTp + (2*g+1)*128)[ng2];
      float4 tc = *chunkc(sh_t, 2*g,   sg);
      float4 ts = *chunkc(sh_t, 2*g+1, sg);
      float4 d0, d1;
      d0.x = s1t[0].x*(tc.x*w1.x - ts.x*w0.x);
      d0.y = s1t[0].y*(tc.y*w1.x - ts.y*w0.x);
      d0.z = s1t[0].z*(tc.z*w1.x - ts.z*w0.x);
      d0.w = s1t[0].w*(tc.w*w1.x - ts.w*w0.x);
      d1.x = s1t[1].x*(tc.x*w1.y - ts.x*w0.y);
      d1.y = s1t[1].y*(tc.y*w1.y - ts.y*w0.y);
      d1.z = s1t[1].z*(tc.z*w1.y - ts.z*w0.y);
      d1.w = s1t[1].w*(tc.w*w1.y - ts.w*w0.y);
      *chunkp(sh_A, ng2,    sg) = d0;
      *chunkp(sh_A, ng2+64, sg) = d1;
    }
    __syncthreads();
    // dh2 = s2 * (W2L dh1) -> sh_B
    {
      float4 z0 = f4all(0.f), z1 = f4all(0.f);
      gemv2<128>(W2LTp, sh_A, ng2, sg, z0, z1);
      *chunkp(sh_B, ng2,    sg) = mul4(s2t[0], z0);
      *chunkp(sh_B, ng2+64, sg) = mul4(s2t[1], z1);
    }
    __syncthreads();
    // dy = s3 * (W3L dh2) -> sh_dy
    if (ng2 < 21){
      float4 acc = f4all(0.f);
      #pragma unroll 4
      for (int i=0;i<128;i++){
        float w = W3LT[i*21+ng2];
        fma4(acc, w, *chunkc(sh_B, i, sg));
      }
      *chunkp(sh_dy, ng2, sg) = mul4(s3t, acc);
    }
    __syncthreads();
    // small per-sample: w_g = dL v + L u_g ; 4 samples per wave
    if ((tid & 63) < 4){
      int s = sg*4 + (tid & 3);
      float qd[6];
      #pragma unroll
      for (int i=0;i<6;i++) qd[i] = sh_qd[i][s];
      float u[6];
      #pragma unroll
      for (int jj=0;jj<6;jj++){
        float acc = 0.f;
        for (int i=jj;i<6;i++) acc = fmaf(el(sh_dy, c_ROWOFF[i]+jj, s), qd[i], acc);
        u[jj] = acc;
      }
      float w[6]; float r = 0.f;
      #pragma unroll
      for (int i=0;i<6;i++){
        float acc = 0.f;
        for (int j=0;j<=i;j++){
          acc = fmaf(el(sh_dy, c_ROWOFF[i]+j, s), sh_v[j][s], acc);
          acc = fmaf(el(sh_y,  c_ROWOFF[i]+j, s), u[j], acc);
        }
        w[i] = acc;
        r = fmaf(qd[i], acc, r);
      }
      float qg = qd[g];
      #pragma unroll
      for (int i=0;i<6;i++) sh_c[i][s] = fmaf(qg, w[i], sh_c[i][s]);
      sh_c[g][s] -= 0.5f*r;
    }
  }
  __syncthreads();

  // ---- V-net layer 1 -> sh_A, s1t (reused)
  {
    float4 z0 = f4all(b1V[ng2]), z1 = f4all(b1V[ng2+64]);
    gemv2<12>(W1VTp, sh_t, ng2, sg, z0, z1);
    *chunkp(sh_A, ng2,    sg) = sp4(z0);  s1t[0] = sig4(z0);
    *chunkp(sh_A, ng2+64, sg) = sp4(z1);  s1t[1] = sig4(z1);
  }
  __syncthreads();
  // ---- V layer 2: g2 = sigmoid(z2V) * W3V -> sh_B
  {
    float4 z0 = f4all(b2V[ng2]), z1 = f4all(b2V[ng2+64]);
    gemv2<128>(W2VTp, sh_A, ng2, sg, z0, z1);
    float w30 = W3V[ng2], w31 = W3V[ng2+64];
    float4 g20 = sig4(z0), g21 = sig4(z1);
    *chunkp(sh_B, ng2,    sg) = make_float4(g20.x*w30, g20.y*w30, g20.z*w30, g20.w*w30);
    *chunkp(sh_B, ng2+64, sg) = make_float4(g21.x*w31, g21.y*w31, g21.z*w31, g21.w*w31);
  }
  __syncthreads();
  // ---- V backward: g1 = s1V * (W2V^T g2) -> sh_A
  {
    float4 z0 = f4all(0.f), z1 = f4all(0.f);
    gemv2<128>(W2Vp, sh_B, ng2, sg, z0, z1);
    *chunkp(sh_A, ng2,    sg) = mul4(s1t[0], z0);
    *chunkp(sh_A, ng2+64, sg) = mul4(s1t[1], z1);
  }
  __syncthreads();
  // ---- dV/dt = W1V^T g1 (12 outputs) -> sh_dy rows 0..11
  if (ng2 < 12){
    float4 acc = f4all(0.f);
    #pragma unroll 4
    for (int j=0;j<128;j++){
      float w = W1V[j*12+ng2];
      fma4(acc, w, *chunkc(sh_A, j, sg));
    }
    *chunkp(sh_dy, ng2, sg) = acc;
  }
  __syncthreads();
  // ---- gravity: chain through trig
  if (tid < 96){
    int k = tid>>4, s = tid&15;
    sh_grav[k][s] = fmaf(el(sh_t,2*k,s), el(sh_dy,2*k+1,s), -(el(sh_t,2*k+1,s)*el(sh_dy,2*k,s)));
  }
  __syncthreads();

  // ---- assembly: rhs, two triangular solves with L (M = L L^T); 4 samples/wave
  if ((tid & 63) < 4){
    int s = sg*4 + (tid & 3);
    float Lm[21];
    #pragma unroll
    for (int o=0;o<21;o++) Lm[o] = el(sh_y, o, s);
    float rhs[6];
    #pragma unroll
    for (int i=0;i<6;i++) rhs[i] = sh_tau[i][s] - sh_c[i][s] - sh_grav[i][s] - sh_f[i][s];
    float z[6];
    #pragma unroll
    for (int i=0;i<6;i++){
      float acc = rhs[i];
      for (int j=0;j<i;j++) acc = fmaf(-Lm[c_ROWOFF[i]+j], z[j], acc);
      z[i] = acc / Lm[c_ROWOFF[i]+i];
    }
    float a[6];
    #pragma unroll
    for (int i=5;i>=0;i--){
      float acc = z[i];
      for (int j=i+1;j<6;j++) acc = fmaf(-Lm[c_ROWOFF[j]+i], a[j], acc);
      a[i] = acc / Lm[c_ROWOFF[i]+i];
    }
    #pragma unroll
    for (int i=0;i<6;i++) kqd_out[(s0+s)*6+i] = a[i];
  }
}

// ---------------- final RK4 combine ----------------
__global__ void __launch_bounds__(256) k_final(const float* __restrict__ obs,
    const float* __restrict__ kqd, float* __restrict__ out)
{
  int b = blockIdx.x*256 + threadIdx.x;
  if (b >= BATCH) return;
  const float* o = obs + b*12;
  float* po = out + b*12;
  #pragma unroll
  for (int i=0;i<6;i++){
    float q0=o[i], qd0=o[6+i];
    float k1=kqd[b*6+i], k2=kqd[B6+b*6+i], k3=kqd[2*B6+b*6+i], k4=kqd[3*B6+b*6+i];
    float qn = q0 + DT*qd0 + (DT*DT/6.0f)*(k1+k2+k3);
    qn = fminf(fmaxf(qn, c_LOWER[i]), c_UPPER[i]);
    po[i] = qn;
    po[6+i] = qd0 + (DT/6.0f)*(k1 + 2.0f*k2 + 2.0f*k3 + k4);
  }
}

extern "C" void kernel_launch(void* const* d_in, const int* in_sizes, int n_in,
                              void* d_out, int out_size, void* d_ws, size_t ws_size,
                              hipStream_t stream) {
  const float* obs    = (const float*)d_in[0];
  const float* action = (const float*)d_in[1];
  const float* W1L = (const float*)d_in[2];  const float* b1L = (const float*)d_in[3];
  const float* W2L = (const float*)d_in[4];  const float* b2L = (const float*)d_in[5];
  const float* W3L = (const float*)d_in[6];  const float* b3L = (const float*)d_in[7];
  const float* W1V = (const float*)d_in[8];  const float* b1V = (const float*)d_in[9];
  const float* W2V = (const float*)d_in[10]; const float* b2V = (const float*)d_in[11];
  const float* W3V = (const float*)d_in[12]; // b3V (d_in[13]) unused: only grad of V needed

  float* ws = (float*)d_ws;
  float* W2LTp = ws;                // 16384
  float* W2VTp = W2LTp + 16384;     // 16384
  float* W2Vp  = W2VTp + 16384;     // 16384
  float* W1LTp = W2Vp  + 16384;     // 1536
  float* W1VTp = W1LTp + 1536;      // 1536
  float* W3LT  = W1VTp + 1536;      // 2688
  float* q_cur  = W3LT + 2688;      // B6
  float* qd_cur = q_cur + B6;       // B6
  float* kqd    = qd_cur + B6;      // 4*B6
  int*   viol   = (int*)(kqd + 4*B6);

  float* out = (float*)d_out;

  k_init<<<64,256,0,stream>>>(W1L,W2L,W1V,W2V,W3L,
                              W1LTp,W2LTp,W1VTp,W2VTp,W2Vp,W3LT,viol);
  for (int s=0; s<4; ++s){
    k_pre<<<64,256,0,stream>>>(s, obs, kqd, q_cur, qd_cur, viol);
    k_accel<<<1024,256,0,stream>>>(q_cur, qd_cur, action,
        W1LTp, b1L, W2LTp, b2L, W3LT, b3L,
        W1VTp, b1V, W2VTp, b2V, W2Vp, W1V, W3V,
        viol + s, kqd + s*B6);
  }
  k_final<<<64,256,0,stream>>>(obs, kqd, out);
}

// Round 4
// 887.748 us; speedup vs baseline: 1.2162x; 1.2162x over previous
//
#include <hip/hip_runtime.h>
#include <math.h>

#define BATCH 16384
#define B6 (BATCH*6)
#define DT 0.01f
#define SPB 8   // samples per block

__device__ __constant__ float c_LOWER[6]  = {-6.28f,-6.28f,-3.14f,-6.28f,-6.28f,-6.28f};
__device__ __constant__ float c_UPPER[6]  = { 6.28f, 6.28f, 3.14f, 6.28f, 6.28f, 6.28f};
__device__ __constant__ float c_EFFORT[6] = {150.0f,150.0f,150.0f,28.0f,28.0f,28.0f};
__device__ __constant__ int   c_ROWOFF[6] = {0,1,3,6,10,15};

__device__ __forceinline__ float sp_f(float z){ return fmaxf(z,0.0f) + log1pf(expf(-fabsf(z))); }
__device__ __forceinline__ float sig_f(float z){ return 1.0f/(1.0f+expf(-z)); }

__device__ __forceinline__ float4 f4all(float v){ return make_float4(v,v,v,v); }
__device__ __forceinline__ void fma4(float4& acc, float w, float4 a){
  acc.x=fmaf(w,a.x,acc.x); acc.y=fmaf(w,a.y,acc.y); acc.z=fmaf(w,a.z,acc.z); acc.w=fmaf(w,a.w,acc.w);
}
__device__ __forceinline__ float4 mul4(float4 a, float4 b){
  return make_float4(a.x*b.x, a.y*b.y, a.z*b.z, a.w*b.w);
}
__device__ __forceinline__ float4 sp4(float4 z){
  return make_float4(sp_f(z.x),sp_f(z.y),sp_f(z.z),sp_f(z.w));
}
__device__ __forceinline__ float4 sig4(float4 z){
  return make_float4(sig_f(z.x),sig_f(z.y),sig_f(z.z),sig_f(z.w));
}

// ---- LDS accessors -------------------------------------------------------
// Big (128 logical rows x 8 samples) arrays stored [64][16]:
//   row r = n&63, chunk c = 2*(n>>6) + (s>>2), phys chunk pc = c ^ ((r>>1)&3).
// Column-write by 64 lanes (row = lane) covers all 8 bank-quads exactly
// (8 lanes/quad = b128 minimum) -> conflict-free; uniform reads broadcast.
__device__ __forceinline__ float4* ck128(float (*a)[16], int n, int cc){
  int r = n & 63;
  int pc = (((n>>6)<<1) + cc) ^ ((r>>1)&3);
  return reinterpret_cast<float4*>(&a[r][4*pc]);
}
__device__ __forceinline__ const float4* ck128c(const float (*a)[16], int n, int cc){
  int r = n & 63;
  int pc = (((n>>6)<<1) + cc) ^ ((r>>1)&3);
  return reinterpret_cast<const float4*>(&a[r][4*pc]);
}
// Small (N<=24 rows x 8 samples) arrays stored [N][8], chunk swizzle by row bit.
__device__ __forceinline__ float4* ckS(float (*a)[8], int n, int cc){
  return reinterpret_cast<float4*>(&a[n][4*(cc ^ (n&1))]);
}
__device__ __forceinline__ const float4* ckSc(const float (*a)[8], int n, int cc){
  return reinterpret_cast<const float4*>(&a[n][4*(cc ^ (n&1))]);
}
__device__ __forceinline__ float& elS(float (*a)[8], int n, int s){
  return a[n][4*((s>>2) ^ (n&1)) + (s&3)];
}

// 2 rows (ng2, ng2+64) x 4 samples over 128 inputs; Wp packed (k,k+64)->(2k,2k+1).
__device__ __forceinline__ void gemv2_128(const float* __restrict__ Wp,
                                          const float (*__restrict__ src)[16],
                                          int ng2, int cc, float4& z0, float4& z1){
  #pragma unroll 4
  for (int i=0;i<128;i++){
    float2 w = reinterpret_cast<const float2*>(Wp + i*128)[ng2];
    float4 a = *ck128c(src, i, cc);
    fma4(z0, w.x, a);
    fma4(z1, w.y, a);
  }
}
__device__ __forceinline__ void gemv2_12(const float* __restrict__ Wp,
                                         const float (*__restrict__ src)[8],
                                         int ng2, int cc, float4& z0, float4& z1){
  #pragma unroll
  for (int i=0;i<12;i++){
    float2 w = reinterpret_cast<const float2*>(Wp + i*128)[ng2];
    float4 a = *ckSc(src, i, cc);
    fma4(z0, w.x, a);
    fma4(z1, w.y, a);
  }
}

// ---------------- init: transpose+pack weights, zero viol ----------------
__global__ void __launch_bounds__(256) k_init(
    const float* __restrict__ W1L, const float* __restrict__ W2L,
    const float* __restrict__ W1V, const float* __restrict__ W2V,
    const float* __restrict__ W3L,
    float* __restrict__ W1LTp, float* __restrict__ W2LTp,
    float* __restrict__ W1VTp, float* __restrict__ W2VTp,
    float* __restrict__ W2Vp,  float* __restrict__ W3LT, int* __restrict__ viol)
{
  int t = blockIdx.x*256 + threadIdx.x;
  if (t < 4) viol[t] = 0;
  if (t < 1536){
    int i = t/128, c = t%128, k = (c>>1) + 64*(c&1);
    W1LTp[t] = W1L[k*12+i]; W1VTp[t] = W1V[k*12+i];
  }
  if (t < 2688){ int i = t/21, o = t%21; W3LT[t] = W3L[o*128+i]; }
  if (t < 16384){
    int i = t/128, c = t%128, k = (c>>1) + 64*(c&1);
    W2LTp[t] = W2L[k*128+i];
    W2VTp[t] = W2V[k*128+i];
    W2Vp[t]  = W2V[i*128+k];
  }
}

// ---------------- per-stage state + batch viol reduction ----------------
__global__ void __launch_bounds__(256) k_pre(int stage,
    const float* __restrict__ obs, const float* __restrict__ kqd,
    float* __restrict__ q_cur, float* __restrict__ qd_cur, int* __restrict__ viol)
{
  int b = blockIdx.x*256 + threadIdx.x;
  if (b >= BATCH) return;
  const float* o = obs + b*12;
  unsigned mask = 0;
  #pragma unroll
  for (int i=0;i<6;i++){
    float q0 = o[i], qd0 = o[6+i];
    float q, qd;
    if (stage == 0){ q=q0; qd=qd0; }
    else if (stage == 1){
      q  = q0 + 0.5f*DT*qd0;
      qd = qd0 + 0.5f*DT*kqd[b*6+i];
    } else if (stage == 2){
      q  = q0 + 0.5f*DT*qd0 + 0.25f*DT*DT*kqd[b*6+i];
      qd = qd0 + 0.5f*DT*kqd[B6 + b*6+i];
    } else {
      q  = q0 + DT*qd0 + 0.5f*DT*DT*kqd[B6 + b*6+i];
      qd = qd0 + DT*kqd[2*B6 + b*6+i];
    }
    q_cur[b*6+i]=q; qd_cur[b*6+i]=qd;
    float lo = c_LOWER[i]+0.1f, up = c_UPPER[i]-0.1f;
    if (q <= lo || q >= up) mask |= (1u<<i);
  }
  unsigned wm = 0;
  #pragma unroll
  for (int i=0;i<6;i++) if (__ballot((int)((mask>>i)&1u))) wm |= (1u<<i);
  if ((threadIdx.x & 63)==0 && wm) atomicOr(viol + stage, (int)wm);
}

// ---------------- heavy per-stage accel ----------------
// 8 samples/block, 128 threads (2 waves), 2048 blocks -> 16 waves/CU.
// Wave = one 4-sample chunk cc (wave-uniform -> LDS gemv reads broadcast).
// Thread (lane ng2): rows {ng2, ng2+64}; sigmoid tiles in registers.
__global__ void __launch_bounds__(128) k_accel(
    const float* __restrict__ q_cur, const float* __restrict__ qd_cur,
    const float* __restrict__ action,
    const float* __restrict__ W1LTp, const float* __restrict__ b1L,
    const float* __restrict__ W2LTp, const float* __restrict__ b2L,
    const float* __restrict__ W3LT,  const float* __restrict__ b3L,
    const float* __restrict__ W1VTp, const float* __restrict__ b1V,
    const float* __restrict__ W2VTp, const float* __restrict__ b2V,
    const float* __restrict__ W2Vp,  const float* __restrict__ W1V,
    const float* __restrict__ W3V,
    const int* __restrict__ viol_stage,
    float* __restrict__ kqd_out)
{
  __shared__ alignas(16) float sh_t[12][8];
  __shared__ alignas(16) float sh_A[64][16];   // 128 logical rows x 8 samples
  __shared__ alignas(16) float sh_B[64][16];
  __shared__ alignas(16) float sh_y[21][8];
  __shared__ alignas(16) float sh_dy[21][8];
  __shared__ float sh_qd[6][8], sh_tau[6][8], sh_f[6][8];
  __shared__ float sh_c[6][8], sh_grav[6][8], sh_v[6][8];

  const int tid = threadIdx.x;
  const int ng2 = tid & 63;      // lane = row pair {ng2, ng2+64}
  const int cc  = tid >> 6;      // wave = sample chunk (4 samples)
  const int s0  = blockIdx.x * SPB;
  const int vm  = *viol_stage;

  // ---- load tile, trig features, tau, constraint force (48 slots)
  if (tid < 48){
    int s = tid & 7, i = tid >> 3;
    float q  = q_cur [(s0+s)*6 + i];
    float qd = qd_cur[(s0+s)*6 + i];
    sh_qd[i][s]=qd;
    sh_tau[i][s] = action[(s0+s)*6+i] * c_EFFORT[i];
    elS(sh_t, 2*i,   s) = cosf(q);
    elS(sh_t, 2*i+1, s) = sinf(q);
    float lo = c_LOWER[i]+0.1f, up = c_UPPER[i]-0.1f;
    float barrier = -5.0f*(1.0f/(q-lo) - 1.0f/(up-q));
    float clip = (q<=lo)? c_EFFORT[i] : ((q>=up)? -c_EFFORT[i] : 0.0f);
    sh_f[i][s] = ((vm>>i)&1) ? clip : barrier;
    sh_c[i][s] = 0.0f;
  }
  __syncthreads();

  float4 s1t[2], s2t[2];

  // ---- L-net layer 1
  {
    float4 z0 = f4all(b1L[ng2]), z1 = f4all(b1L[ng2+64]);
    gemv2_12(W1LTp, sh_t, ng2, cc, z0, z1);
    *ck128(sh_A, ng2,    cc) = sp4(z0);  s1t[0] = sig4(z0);
    *ck128(sh_A, ng2+64, cc) = sp4(z1);  s1t[1] = sig4(z1);
  }
  __syncthreads();

  // ---- L-net layer 2
  {
    float4 z0 = f4all(b2L[ng2]), z1 = f4all(b2L[ng2+64]);
    gemv2_128(W2LTp, sh_A, ng2, cc, z0, z1);
    *ck128(sh_B, ng2,    cc) = sp4(z0);  s2t[0] = sig4(z0);
    *ck128(sh_B, ng2+64, cc) = sp4(z1);  s2t[1] = sig4(z1);
  }
  __syncthreads();

  // ---- L-net layer 3 (21 outputs): lane<21 in each wave, own chunk
  float4 s3t = f4all(0.f);
  if (ng2 < 21){
    float4 acc = f4all(b3L[ng2]);
    #pragma unroll 4
    for (int i=0;i<128;i++){
      float w = W3LT[i*21+ng2];
      fma4(acc, w, *ck128c(sh_B, i, cc));
    }
    *ckS(sh_y, ng2, cc) = sp4(acc);
    s3t = sig4(acc);
  }
  __syncthreads();

  // ---- v = L^T qdot (48 slots)
  if (tid < 48){
    int s = tid & 7, jj = tid >> 3;
    float acc = 0.f;
    for (int i=jj;i<6;i++) acc = fmaf(elS(sh_y, c_ROWOFF[i]+jj, s), sh_qd[i][s], acc);
    sh_v[jj][s] = acc;
  }

  // ---- tangent loop over g: dM/dq_g, accumulate Coriolis c
  for (int g=0; g<6; ++g){
    __syncthreads();
    // dh1 = s1 * (cos*W1[:,2g+1] - sin*W1[:,2g])  -> sh_A
    {
      float2 w0 = reinterpret_cast<const float2*>(W1LTp + (2*g)*128)[ng2];
      float2 w1 = reinterpret_cast<const float2*>(W1LTp + (2*g+1)*128)[ng2];
      float4 tc = *ckSc(sh_t, 2*g,   cc);
      float4 ts = *ckSc(sh_t, 2*g+1, cc);
      float4 d0, d1;
      d0.x = s1t[0].x*(tc.x*w1.x - ts.x*w0.x);
      d0.y = s1t[0].y*(tc.y*w1.x - ts.y*w0.x);
      d0.z = s1t[0].z*(tc.z*w1.x - ts.z*w0.x);
      d0.w = s1t[0].w*(tc.w*w1.x - ts.w*w0.x);
      d1.x = s1t[1].x*(tc.x*w1.y - ts.x*w0.y);
      d1.y = s1t[1].y*(tc.y*w1.y - ts.y*w0.y);
      d1.z = s1t[1].z*(tc.z*w1.y - ts.z*w0.y);
      d1.w = s1t[1].w*(tc.w*w1.y - ts.w*w0.y);
      *ck128(sh_A, ng2,    cc) = d0;
      *ck128(sh_A, ng2+64, cc) = d1;
    }
    __syncthreads();
    // dh2 = s2 * (W2L dh1) -> sh_B
    {
      float4 z0 = f4all(0.f), z1 = f4all(0.f);
      gemv2_128(W2LTp, sh_A, ng2, cc, z0, z1);
      *ck128(sh_B, ng2,    cc) = mul4(s2t[0], z0);
      *ck128(sh_B, ng2+64, cc) = mul4(s2t[1], z1);
    }
    __syncthreads();
    // dy = s3 * (W3L dh2) -> sh_dy
    if (ng2 < 21){
      float4 acc = f4all(0.f);
      #pragma unroll 4
      for (int i=0;i<128;i++){
        float w = W3LT[i*21+ng2];
        fma4(acc, w, *ck128c(sh_B, i, cc));
      }
      *ckS(sh_dy, ng2, cc) = mul4(s3t, acc);
    }
    __syncthreads();
    // small per-sample: w_g = dL v + L u_g ; 4 samples per wave
    if (ng2 < 4){
      int s = cc*4 + ng2;
      float qd[6];
      #pragma unroll
      for (int i=0;i<6;i++) qd[i] = sh_qd[i][s];
      float u[6];
      #pragma unroll
      for (int jj=0;jj<6;jj++){
        float acc = 0.f;
        for (int i=jj;i<6;i++) acc = fmaf(elS(sh_dy, c_ROWOFF[i]+jj, s), qd[i], acc);
        u[jj] = acc;
      }
      float w[6]; float r = 0.f;
      #pragma unroll
      for (int i=0;i<6;i++){
        float acc = 0.f;
        for (int j=0;j<=i;j++){
          acc = fmaf(elS(sh_dy, c_ROWOFF[i]+j, s), sh_v[j][s], acc);
          acc = fmaf(elS(sh_y,  c_ROWOFF[i]+j, s), u[j], acc);
        }
        w[i] = acc;
        r = fmaf(qd[i], acc, r);
      }
      float qg = qd[g];
      #pragma unroll
      for (int i=0;i<6;i++) sh_c[i][s] = fmaf(qg, w[i], sh_c[i][s]);
      sh_c[g][s] -= 0.5f*r;
    }
  }
  __syncthreads();

  // ---- V-net layer 1 -> sh_A, s1t (reused)
  {
    float4 z0 = f4all(b1V[ng2]), z1 = f4all(b1V[ng2+64]);
    gemv2_12(W1VTp, sh_t, ng2, cc, z0, z1);
    *ck128(sh_A, ng2,    cc) = sp4(z0);  s1t[0] = sig4(z0);
    *ck128(sh_A, ng2+64, cc) = sp4(z1);  s1t[1] = sig4(z1);
  }
  __syncthreads();
  // ---- V layer 2: g2 = sigmoid(z2V) * W3V -> sh_B
  {
    float4 z0 = f4all(b2V[ng2]), z1 = f4all(b2V[ng2+64]);
    gemv2_128(W2VTp, sh_A, ng2, cc, z0, z1);
    float w30 = W3V[ng2], w31 = W3V[ng2+64];
    float4 g20 = sig4(z0), g21 = sig4(z1);
    *ck128(sh_B, ng2,    cc) = make_float4(g20.x*w30, g20.y*w30, g20.z*w30, g20.w*w30);
    *ck128(sh_B, ng2+64, cc) = make_float4(g21.x*w31, g21.y*w31, g21.z*w31, g21.w*w31);
  }
  __syncthreads();
  // ---- V backward: g1 = s1V * (W2V^T g2) -> sh_A
  {
    float4 z0 = f4all(0.f), z1 = f4all(0.f);
    gemv2_128(W2Vp, sh_B, ng2, cc, z0, z1);
    *ck128(sh_A, ng2,    cc) = mul4(s1t[0], z0);
    *ck128(sh_A, ng2+64, cc) = mul4(s1t[1], z1);
  }
  __syncthreads();
  // ---- dV/dt = W1V^T g1 (12 outputs) -> sh_dy rows 0..11
  if (ng2 < 12){
    float4 acc = f4all(0.f);
    #pragma unroll 4
    for (int j=0;j<128;j++){
      float w = W1V[j*12+ng2];
      fma4(acc, w, *ck128c(sh_A, j, cc));
    }
    *ckS(sh_dy, ng2, cc) = acc;
  }
  __syncthreads();
  // ---- gravity: chain through trig (48 slots)
  if (tid < 48){
    int k = tid>>3, s = tid&7;
    sh_grav[k][s] = fmaf(elS(sh_t,2*k,s), elS(sh_dy,2*k+1,s),
                         -(elS(sh_t,2*k+1,s)*elS(sh_dy,2*k,s)));
  }
  __syncthreads();

  // ---- assembly: rhs, two triangular solves with L (M = L L^T); 4 samples/wave
  if (ng2 < 4){
    int s = cc*4 + ng2;
    float Lm[21];
    #pragma unroll
    for (int o=0;o<21;o++) Lm[o] = elS(sh_y, o, s);
    float rhs[6];
    #pragma unroll
    for (int i=0;i<6;i++) rhs[i] = sh_tau[i][s] - sh_c[i][s] - sh_grav[i][s] - sh_f[i][s];
    float z[6];
    #pragma unroll
    for (int i=0;i<6;i++){
      float acc = rhs[i];
      for (int j=0;j<i;j++) acc = fmaf(-Lm[c_ROWOFF[i]+j], z[j], acc);
      z[i] = acc / Lm[c_ROWOFF[i]+i];
    }
    float a[6];
    #pragma unroll
    for (int i=5;i>=0;i--){
      float acc = z[i];
      for (int j=i+1;j<6;j++) acc = fmaf(-Lm[c_ROWOFF[j]+i], a[j], acc);
      a[i] = acc / Lm[c_ROWOFF[i]+i];
    }
    #pragma unroll
    for (int i=0;i<6;i++) kqd_out[(s0+s)*6+i] = a[i];
  }
}

// ---------------- final RK4 combine ----------------
__global__ void __launch_bounds__(256) k_final(const float* __restrict__ obs,
    const float* __restrict__ kqd, float* __restrict__ out)
{
  int b = blockIdx.x*256 + threadIdx.x;
  if (b >= BATCH) return;
  const float* o = obs + b*12;
  float* po = out + b*12;
  #pragma unroll
  for (int i=0;i<6;i++){
    float q0=o[i], qd0=o[6+i];
    float k1=kqd[b*6+i], k2=kqd[B6+b*6+i], k3=kqd[2*B6+b*6+i], k4=kqd[3*B6+b*6+i];
    float qn = q0 + DT*qd0 + (DT*DT/6.0f)*(k1+k2+k3);
    qn = fminf(fmaxf(qn, c_LOWER[i]), c_UPPER[i]);
    po[i] = qn;
    po[6+i] = qd0 + (DT/6.0f)*(k1 + 2.0f*k2 + 2.0f*k3 + k4);
  }
}

extern "C" void kernel_launch(void* const* d_in, const int* in_sizes, int n_in,
                              void* d_out, int out_size, void* d_ws, size_t ws_size,
                              hipStream_t stream) {
  const float* obs    = (const float*)d_in[0];
  const float* action = (const float*)d_in[1];
  const float* W1L = (const float*)d_in[2];  const float* b1L = (const float*)d_in[3];
  const float* W2L = (const float*)d_in[4];  const float* b2L = (const float*)d_in[5];
  const float* W3L = (const float*)d_in[6];  const float* b3L = (const float*)d_in[7];
  const float* W1V = (const float*)d_in[8];  const float* b1V = (const float*)d_in[9];
  const float* W2V = (const float*)d_in[10]; const float* b2V = (const float*)d_in[11];
  const float* W3V = (const float*)d_in[12]; // b3V (d_in[13]) unused: only grad of V needed

  float* ws = (float*)d_ws;
  float* W2LTp = ws;                // 16384
  float* W2VTp = W2LTp + 16384;     // 16384
  float* W2Vp  = W2VTp + 16384;     // 16384
  float* W1LTp = W2Vp  + 16384;     // 1536
  float* W1VTp = W1LTp + 1536;      // 1536
  float* W3LT  = W1VTp + 1536;      // 2688
  float* q_cur  = W3LT + 2688;      // B6
  float* qd_cur = q_cur + B6;       // B6
  float* kqd    = qd_cur + B6;      // 4*B6
  int*   viol   = (int*)(kqd + 4*B6);

  float* out = (float*)d_out;

  k_init<<<64,256,0,stream>>>(W1L,W2L,W1V,W2V,W3L,
                              W1LTp,W2LTp,W1VTp,W2VTp,W2Vp,W3LT,viol);
  for (int s=0; s<4; ++s){
    k_pre<<<64,256,0,stream>>>(s, obs, kqd, q_cur, qd_cur, viol);
    k_accel<<<2048,128,0,stream>>>(q_cur, qd_cur, action,
        W1LTp, b1L, W2LTp, b2L, W3LT, b3L,
        W1VTp, b1V, W2VTp, b2V, W2Vp, W1V, W3V,
        viol + s, kqd + s*B6);
  }
  k_final<<<64,256,0,stream>>>(obs, kqd, out);
}

// Round 5
// 612.519 us; speedup vs baseline: 1.7627x; 1.4493x over previous
//
#include <hip/hip_runtime.h>
#include <math.h>

#define BATCH 16384
#define B6 (BATCH*6)
#define DT 0.01f

__device__ __constant__ float c_LOWER[6]  = {-6.28f,-6.28f,-3.14f,-6.28f,-6.28f,-6.28f};
__device__ __constant__ float c_UPPER[6]  = { 6.28f, 6.28f, 3.14f, 6.28f, 6.28f, 6.28f};
__device__ __constant__ float c_EFFORT[6] = {150.0f,150.0f,150.0f,28.0f,28.0f,28.0f};
__device__ __constant__ int   c_ROWOFF[6] = {0,1,3,6,10,15};

__device__ __forceinline__ float sp_f(float z){ return fmaxf(z,0.0f) + log1pf(expf(-fabsf(z))); }
__device__ __forceinline__ float sig_f(float z){ return 1.0f/(1.0f+expf(-z)); }

__device__ __forceinline__ float4 f4all(float v){ return make_float4(v,v,v,v); }
__device__ __forceinline__ void fma4(float4& acc, float w, float4 a){
  acc.x=fmaf(w,a.x,acc.x); acc.y=fmaf(w,a.y,acc.y); acc.z=fmaf(w,a.z,acc.z); acc.w=fmaf(w,a.w,acc.w);
}
__device__ __forceinline__ float4 mul4(float4 a, float4 b){
  return make_float4(a.x*b.x, a.y*b.y, a.z*b.z, a.w*b.w);
}
__device__ __forceinline__ float4 sp4(float4 z){
  return make_float4(sp_f(z.x),sp_f(z.y),sp_f(z.z),sp_f(z.w));
}
__device__ __forceinline__ float4 sig4(float4 z){
  return make_float4(sig_f(z.x),sig_f(z.y),sig_f(z.z),sig_f(z.w));
}

// XOR-swizzled LDS accessors for [N][16] arrays (verified conflict-free in
// r3/r4: column b128 writes by 64 lanes cover all 8 bank-quads; wave-uniform
// chunk reads broadcast).
__device__ __forceinline__ float4* chunkp(float (*arr)[16], int n, int cc){
  return reinterpret_cast<float4*>(&arr[n][4*(cc ^ ((n>>1)&3))]);
}
__device__ __forceinline__ const float4* chunkc(const float (*arr)[16], int n, int cc){
  return reinterpret_cast<const float4*>(&arr[n][4*(cc ^ ((n>>1)&3))]);
}
__device__ __forceinline__ float& el(float (*arr)[16], int n, int s){
  return arr[n][4*((s>>2) ^ ((n>>1)&3)) + (s&3)];
}

// ---------------- init: transpose+pack weights, zero viol ----------------
__global__ void __launch_bounds__(256) k_init(
    const float* __restrict__ W1L, const float* __restrict__ W2L,
    const float* __restrict__ W1V, const float* __restrict__ W2V,
    const float* __restrict__ W3L,
    float* __restrict__ W1LTp, float* __restrict__ W2LTp,
    float* __restrict__ W1VTp, float* __restrict__ W2VTp,
    float* __restrict__ W2Vp,  float* __restrict__ W3LT3, int* __restrict__ viol)
{
  int t = blockIdx.x*256 + threadIdx.x;
  if (t < 4) viol[t] = 0;
  if (t < 1536){
    int i = t/128, c = t%128, k = (c>>1) + 64*(c&1);
    W1LTp[t] = W1L[k*12+i]; W1VTp[t] = W1V[k*12+i];
  }
  if (t < 8192){                       // W3 replicated x3: [i][p], p<63 -> (o=p%21, g=p/21)
    int i = t >> 6, p = t & 63;
    W3LT3[t] = (p < 63) ? W3L[(p % 21)*128 + i] : 0.0f;
  }
  if (t < 16384){
    int i = t/128, c = t%128, k = (c>>1) + 64*(c&1);
    W2LTp[t] = W2L[k*128+i];
    W2VTp[t] = W2V[k*128+i];
    W2Vp[t]  = W2V[i*128+k];
  }
}

// ---------------- per-stage state + batch viol reduction ----------------
__global__ void __launch_bounds__(256) k_pre(int stage,
    const float* __restrict__ obs, const float* __restrict__ kqd,
    float* __restrict__ q_cur, float* __restrict__ qd_cur, int* __restrict__ viol)
{
  int b = blockIdx.x*256 + threadIdx.x;
  if (b >= BATCH) return;
  const float* o = obs + b*12;
  unsigned mask = 0;
  #pragma unroll
  for (int i=0;i<6;i++){
    float q0 = o[i], qd0 = o[6+i];
    float q, qd;
    if (stage == 0){ q=q0; qd=qd0; }
    else if (stage == 1){
      q  = q0 + 0.5f*DT*qd0;
      qd = qd0 + 0.5f*DT*kqd[b*6+i];
    } else if (stage == 2){
      q  = q0 + 0.5f*DT*qd0 + 0.25f*DT*DT*kqd[b*6+i];
      qd = qd0 + 0.5f*DT*kqd[B6 + b*6+i];
    } else {
      q  = q0 + DT*qd0 + 0.5f*DT*DT*kqd[B6 + b*6+i];
      qd = qd0 + DT*kqd[2*B6 + b*6+i];
    }
    q_cur[b*6+i]=q; qd_cur[b*6+i]=qd;
    float lo = c_LOWER[i]+0.1f, up = c_UPPER[i]-0.1f;
    if (q <= lo || q >= up) mask |= (1u<<i);
  }
  unsigned wm = 0;
  #pragma unroll
  for (int i=0;i<6;i++) if (__ballot((int)((mask>>i)&1u))) wm |= (1u<<i);
  if ((threadIdx.x & 63)==0 && wm) atomicOr(viol + stage, (int)wm);
}

// ---------------- heavy per-stage accel ----------------
// 16 samples/block, 256 threads (4 waves), 1024 blocks = 4 blocks/CU.
// Wave cc owns sample chunk cc (wave-uniform -> LDS reads broadcast).
// Lane l owns rows {l, l+64}. Tangent dirs processed fused in 2 groups of 3.
__global__ void __launch_bounds__(256) k_accel(
    const float* __restrict__ q_cur, const float* __restrict__ qd_cur,
    const float* __restrict__ action,
    const float* __restrict__ W1LTp, const float* __restrict__ b1L,
    const float* __restrict__ W2LTp, const float* __restrict__ b2L,
    const float* __restrict__ W3LT3, const float* __restrict__ b3L,
    const float* __restrict__ W1VTp, const float* __restrict__ b1V,
    const float* __restrict__ W2VTp, const float* __restrict__ b2V,
    const float* __restrict__ W2Vp,  const float* __restrict__ W1V,
    const float* __restrict__ W3V,
    const int* __restrict__ viol_stage,
    float* __restrict__ kqd_out)
{
  __shared__ alignas(16) float sh_t[12][16];
  __shared__ alignas(16) float sh_D[3][128][16];  // h1 / h2 / dh1 / dh2 / V bufs
  __shared__ alignas(16) float sh_y[21][16];
  __shared__ alignas(16) float sh_s3[21][16];
  __shared__ alignas(16) float sh_dy[63][16];     // dy for 3 dirs; later dV (rows 0..11)
  __shared__ float sh_wg[3][6][16];
  __shared__ float sh_qd[6][16], sh_tau[6][16], sh_f[6][16];
  __shared__ float sh_c[6][16], sh_grav[6][16], sh_v[6][16];

  const int tid = threadIdx.x;
  const int l   = tid & 63;     // lane = row pair {l, l+64}
  const int cc  = tid >> 6;     // wave = sample chunk (4 samples)
  const int s0  = blockIdx.x * 16;
  const int vm  = *viol_stage;

  // ---- phase 0: load tile, trig, tau, constraint force
  if (tid < 96){
    int s = tid & 15, i = tid >> 4;
    float q  = q_cur [(s0+s)*6 + i];
    float qd = qd_cur[(s0+s)*6 + i];
    sh_qd[i][s]=qd;
    sh_tau[i][s] = action[(s0+s)*6+i] * c_EFFORT[i];
    el(sh_t, 2*i,   s) = cosf(q);
    el(sh_t, 2*i+1, s) = sinf(q);
    float lo = c_LOWER[i]+0.1f, up = c_UPPER[i]-0.1f;
    float barrier = -5.0f*(1.0f/(q-lo) - 1.0f/(up-q));
    float clip = (q<=lo)? c_EFFORT[i] : ((q>=up)? -c_EFFORT[i] : 0.0f);
    sh_f[i][s] = ((vm>>i)&1) ? clip : barrier;
    sh_c[i][s] = 0.0f;
  }
  __syncthreads();

  float4 s1t[2], s2t[2];

  // ---- L1 fwd: h1 -> D0, s1 in regs
  {
    float4 z0 = f4all(b1L[l]), z1 = f4all(b1L[l+64]);
    #pragma unroll
    for (int i=0;i<12;i++){
      float2 w = reinterpret_cast<const float2*>(W1LTp + i*128)[l];
      float4 a = *chunkc(sh_t, i, cc);
      fma4(z0, w.x, a); fma4(z1, w.y, a);
    }
    *chunkp(sh_D[0], l,    cc) = sp4(z0);  s1t[0] = sig4(z0);
    *chunkp(sh_D[0], l+64, cc) = sp4(z1);  s1t[1] = sig4(z1);
  }
  __syncthreads();

  // ---- L2 fwd: h2 -> D1, s2 in regs
  {
    float4 z0 = f4all(b2L[l]), z1 = f4all(b2L[l+64]);
    const float2* W2p = reinterpret_cast<const float2*>(W2LTp);
    #pragma unroll 4
    for (int i=0;i<128;i++){
      float2 w = W2p[i*64+l];
      float4 a = *chunkc(sh_D[0], i, cc);
      fma4(z0, w.x, a); fma4(z1, w.y, a);
    }
    *chunkp(sh_D[1], l,    cc) = sp4(z0);  s2t[0] = sig4(z0);
    *chunkp(sh_D[1], l+64, cc) = sp4(z1);  s2t[1] = sig4(z1);
  }
  __syncthreads();

  // ---- L3 fwd: y, s3 (21 rows; lane<21 per wave)
  if (l < 21){
    float4 acc = f4all(b3L[l]);
    #pragma unroll 4
    for (int i=0;i<128;i++){
      float w = W3LT3[i*64+l];
      fma4(acc, w, *chunkc(sh_D[1], i, cc));
    }
    *chunkp(sh_y,  l, cc) = sp4(acc);
    *chunkp(sh_s3, l, cc) = sig4(acc);
  }
  __syncthreads();

  // ---- tangent groups: dirs {0,1,2} then {3,4,5}
  for (int G=0; G<2; ++G){
    if (G==0 && tid < 96){     // v = L^T qdot (needs y; runs alongside dh1 build)
      int s = tid & 15, jj = tid >> 4;
      float acc = 0.f;
      for (int i=jj;i<6;i++) acc = fmaf(el(sh_y, c_ROWOFF[i]+jj, s), sh_qd[i][s], acc);
      sh_v[jj][s] = acc;
    }
    // dh1 for 3 dirs -> D0..D2 (overwrites h1/h2 — no longer needed)
    #pragma unroll
    for (int gg=0; gg<3; ++gg){
      int g = 3*G+gg;
      float2 w0 = reinterpret_cast<const float2*>(W1LTp + (2*g)*128)[l];
      float2 w1 = reinterpret_cast<const float2*>(W1LTp + (2*g+1)*128)[l];
      float4 tc = *chunkc(sh_t, 2*g,   cc);
      float4 ts = *chunkc(sh_t, 2*g+1, cc);
      float4 d0, d1;
      d0.x = s1t[0].x*(tc.x*w1.x - ts.x*w0.x);
      d0.y = s1t[0].y*(tc.y*w1.x - ts.y*w0.x);
      d0.z = s1t[0].z*(tc.z*w1.x - ts.z*w0.x);
      d0.w = s1t[0].w*(tc.w*w1.x - ts.w*w0.x);
      d1.x = s1t[1].x*(tc.x*w1.y - ts.x*w0.y);
      d1.y = s1t[1].y*(tc.y*w1.y - ts.y*w0.y);
      d1.z = s1t[1].z*(tc.z*w1.y - ts.z*w0.y);
      d1.w = s1t[1].w*(tc.w*w1.y - ts.w*w0.y);
      *chunkp(sh_D[gg], l,    cc) = d0;
      *chunkp(sh_D[gg], l+64, cc) = d1;
    }
    __syncthreads();
    // fused W2 pass over 3 dirs: 24 FMA per (1 weight + 3 LDS) per i
    {
      float4 acc[3][2];
      #pragma unroll
      for (int gg=0; gg<3; ++gg){ acc[gg][0] = f4all(0.f); acc[gg][1] = f4all(0.f); }
      const float2* W2p = reinterpret_cast<const float2*>(W2LTp);
      #pragma unroll 2
      for (int i=0;i<128;i++){
        float2 w = W2p[i*64+l];
        #pragma unroll
        for (int gg=0; gg<3; ++gg){
          float4 a = *chunkc(sh_D[gg], i, cc);
          fma4(acc[gg][0], w.x, a);
          fma4(acc[gg][1], w.y, a);
        }
      }
      __syncthreads();   // all waves done reading dh1 before overwrite
      #pragma unroll
      for (int gg=0; gg<3; ++gg){
        *chunkp(sh_D[gg], l,    cc) = mul4(s2t[0], acc[gg][0]);
        *chunkp(sh_D[gg], l+64, cc) = mul4(s2t[1], acc[gg][1]);
      }
    }
    __syncthreads();
    // fused W3 pass: 63 (o,gg) pairs per wave, coalesced replicated weights
    if (l < 63){
      int o = l % 21, gg = l / 21;
      float4 acc3 = f4all(0.f);
      #pragma unroll 4
      for (int i=0;i<128;i++){
        float w = W3LT3[i*64+l];
        fma4(acc3, w, *chunkc(sh_D[gg], i, cc));
      }
      *chunkp(sh_dy, gg*21+o, cc) = mul4(*chunkc(sh_s3, o, cc), acc3);
    }
    __syncthreads();
    // Coriolis phase A: 48 threads (gg, s): u_g, w_g -> sh_wg
    if (tid < 48){
      int s = tid & 15, gg = tid >> 4;
      float qd[6];
      #pragma unroll
      for (int i=0;i<6;i++) qd[i] = sh_qd[i][s];
      float u[6];
      #pragma unroll
      for (int jj=0;jj<6;jj++){
        float acc = 0.f;
        for (int i=jj;i<6;i++)
          acc = fmaf(el(sh_dy, gg*21 + c_ROWOFF[i]+jj, s), qd[i], acc);
        u[jj] = acc;
      }
      #pragma unroll
      for (int i=0;i<6;i++){
        float acc = 0.f;
        for (int j=0;j<=i;j++){
          acc = fmaf(el(sh_dy, gg*21 + c_ROWOFF[i]+j, s), sh_v[j][s], acc);
          acc = fmaf(el(sh_y,  c_ROWOFF[i]+j, s), u[j], acc);
        }
        sh_wg[gg][i][s] = acc;
      }
    }
    __syncthreads();
    // Coriolis phase B: 96 threads (i, s): fold wg into c
    if (tid < 96){
      int s = tid & 15, i = tid >> 4;
      float acc = sh_c[i][s];
      #pragma unroll
      for (int gg=0; gg<3; ++gg)
        acc = fmaf(sh_qd[3*G+gg][s], sh_wg[gg][i][s], acc);
      int gi = i - 3*G;
      if (gi >= 0 && gi < 3){
        float r = 0.f;
        #pragma unroll
        for (int j=0;j<6;j++) r = fmaf(sh_qd[j][s], sh_wg[gi][j][s], r);
        acc -= 0.5f*r;
      }
      sh_c[i][s] = acc;
    }
    __syncthreads();
  }

  // ---- V-net layer 1 -> D0, s1V in regs
  {
    float4 z0 = f4all(b1V[l]), z1 = f4all(b1V[l+64]);
    #pragma unroll
    for (int i=0;i<12;i++){
      float2 w = reinterpret_cast<const float2*>(W1VTp + i*128)[l];
      float4 a = *chunkc(sh_t, i, cc);
      fma4(z0, w.x, a); fma4(z1, w.y, a);
    }
    *chunkp(sh_D[0], l,    cc) = sp4(z0);  s1t[0] = sig4(z0);
    *chunkp(sh_D[0], l+64, cc) = sp4(z1);  s1t[1] = sig4(z1);
  }
  __syncthreads();
  // ---- V layer 2: g2 = sigmoid(z2V) * W3V -> D1
  {
    float4 z0 = f4all(b2V[l]), z1 = f4all(b2V[l+64]);
    const float2* W2p = reinterpret_cast<const float2*>(W2VTp);
    #pragma unroll 4
    for (int i=0;i<128;i++){
      float2 w = W2p[i*64+l];
      float4 a = *chunkc(sh_D[0], i, cc);
      fma4(z0, w.x, a); fma4(z1, w.y, a);
    }
    float w30 = W3V[l], w31 = W3V[l+64];
    float4 g20 = sig4(z0), g21 = sig4(z1);
    *chunkp(sh_D[1], l,    cc) = make_float4(g20.x*w30, g20.y*w30, g20.z*w30, g20.w*w30);
    *chunkp(sh_D[1], l+64, cc) = make_float4(g21.x*w31, g21.y*w31, g21.z*w31, g21.w*w31);
  }
  __syncthreads();
  // ---- V backward: g1 = s1V * (W2V^T g2) -> D2
  {
    float4 z0 = f4all(0.f), z1 = f4all(0.f);
    const float2* W2p = reinterpret_cast<const float2*>(W2Vp);
    #pragma unroll 4
    for (int j=0;j<128;j++){
      float2 w = W2p[j*64+l];
      float4 a = *chunkc(sh_D[1], j, cc);
      fma4(z0, w.x, a); fma4(z1, w.y, a);
    }
    *chunkp(sh_D[2], l,    cc) = mul4(s1t[0], z0);
    *chunkp(sh_D[2], l+64, cc) = mul4(s1t[1], z1);
  }
  __syncthreads();
  // ---- dV/dt = W1V^T g1 (12 outputs) -> sh_dy rows 0..11
  if (l < 12){
    float4 acc = f4all(0.f);
    #pragma unroll 4
    for (int j=0;j<128;j++){
      float w = W1V[j*12+l];
      fma4(acc, w, *chunkc(sh_D[2], j, cc));
    }
    *chunkp(sh_dy, l, cc) = acc;
  }
  __syncthreads();
  // ---- gravity: chain through trig
  if (tid < 96){
    int k = tid>>4, s = tid&15;
    sh_grav[k][s] = fmaf(el(sh_t,2*k,s), el(sh_dy,2*k+1,s),
                         -(el(sh_t,2*k+1,s)*el(sh_dy,2*k,s)));
  }
  __syncthreads();

  // ---- assembly: rhs, two triangular solves with L (M = L L^T); 4 samples/wave
  if (l < 4){
    int s = cc*4 + l;
    float Lm[21];
    #pragma unroll
    for (int o=0;o<21;o++) Lm[o] = el(sh_y, o, s);
    float rhs[6];
    #pragma unroll
    for (int i=0;i<6;i++) rhs[i] = sh_tau[i][s] - sh_c[i][s] - sh_grav[i][s] - sh_f[i][s];
    float z[6];
    #pragma unroll
    for (int i=0;i<6;i++){
      float acc = rhs[i];
      for (int j=0;j<i;j++) acc = fmaf(-Lm[c_ROWOFF[i]+j], z[j], acc);
      z[i] = acc / Lm[c_ROWOFF[i]+i];
    }
    float a[6];
    #pragma unroll
    for (int i=5;i>=0;i--){
      float acc = z[i];
      for (int j=i+1;j<6;j++) acc = fmaf(-Lm[c_ROWOFF[j]+i], a[j], acc);
      a[i] = acc / Lm[c_ROWOFF[i]+i];
    }
    #pragma unroll
    for (int i=0;i<6;i++) kqd_out[(s0+s)*6+i] = a[i];
  }
}

// ---------------- final RK4 combine ----------------
__global__ void __launch_bounds__(256) k_final(const float* __restrict__ obs,
    const float* __restrict__ kqd, float* __restrict__ out)
{
  int b = blockIdx.x*256 + threadIdx.x;
  if (b >= BATCH) return;
  const float* o = obs + b*12;
  float* po = out + b*12;
  #pragma unroll
  for (int i=0;i<6;i++){
    float q0=o[i], qd0=o[6+i];
    float k1=kqd[b*6+i], k2=kqd[B6+b*6+i], k3=kqd[2*B6+b*6+i], k4=kqd[3*B6+b*6+i];
    float qn = q0 + DT*qd0 + (DT*DT/6.0f)*(k1+k2+k3);
    qn = fminf(fmaxf(qn, c_LOWER[i]), c_UPPER[i]);
    po[i] = qn;
    po[6+i] = qd0 + (DT/6.0f)*(k1 + 2.0f*k2 + 2.0f*k3 + k4);
  }
}

extern "C" void kernel_launch(void* const* d_in, const int* in_sizes, int n_in,
                              void* d_out, int out_size, void* d_ws, size_t ws_size,
                              hipStream_t stream) {
  const float* obs    = (const float*)d_in[0];
  const float* action = (const float*)d_in[1];
  const float* W1L = (const float*)d_in[2];  const float* b1L = (const float*)d_in[3];
  const float* W2L = (const float*)d_in[4];  const float* b2L = (const float*)d_in[5];
  const float* W3L = (const float*)d_in[6];  const float* b3L = (const float*)d_in[7];
  const float* W1V = (const float*)d_in[8];  const float* b1V = (const float*)d_in[9];
  const float* W2V = (const float*)d_in[10]; const float* b2V = (const float*)d_in[11];
  const float* W3V = (const float*)d_in[12]; // b3V (d_in[13]) unused: only grad of V needed

  float* ws = (float*)d_ws;
  float* W2LTp = ws;                // 16384
  float* W2VTp = W2LTp + 16384;     // 16384
  float* W2Vp  = W2VTp + 16384;     // 16384
  float* W1LTp = W2Vp  + 16384;     // 1536
  float* W1VTp = W1LTp + 1536;      // 1536
  float* W3LT3 = W1VTp + 1536;      // 8192
  float* q_cur  = W3LT3 + 8192;     // B6
  float* qd_cur = q_cur + B6;       // B6
  float* kqd    = qd_cur + B6;      // 4*B6
  int*   viol   = (int*)(kqd + 4*B6);

  float* out = (float*)d_out;

  k_init<<<64,256,0,stream>>>(W1L,W2L,W1V,W2V,W3L,
                              W1LTp,W2LTp,W1VTp,W2VTp,W2Vp,W3LT3,viol);
  for (int s=0; s<4; ++s){
    k_pre<<<64,256,0,stream>>>(s, obs, kqd, q_cur, qd_cur, viol);
    k_accel<<<1024,256,0,stream>>>(q_cur, qd_cur, action,
        W1LTp, b1L, W2LTp, b2L, W3LT3, b3L,
        W1VTp, b1V, W2VTp, b2V, W2Vp, W1V, W3V,
        viol + s, kqd + s*B6);
  }
  k_final<<<64,256,0,stream>>>(obs, kqd, out);
}

// Round 6
// 352.709 us; speedup vs baseline: 3.0612x; 1.7366x over previous
//
#include <hip/hip_runtime.h>
#include <math.h>

#define BATCH 16384
#define B6 (BATCH*6)
#define DT 0.01f

using half8_t = __attribute__((ext_vector_type(8))) _Float16;
using half4_t = __attribute__((ext_vector_type(4))) _Float16;
using half2_t = __attribute__((ext_vector_type(2))) _Float16;
using f32x4   = __attribute__((ext_vector_type(4))) float;

__device__ __constant__ float c_LOWER[6]  = {-6.28f,-6.28f,-3.14f,-6.28f,-6.28f,-6.28f};
__device__ __constant__ float c_UPPER[6]  = { 6.28f, 6.28f, 3.14f, 6.28f, 6.28f, 6.28f};
__device__ __constant__ float c_EFFORT[6] = {150.0f,150.0f,150.0f,28.0f,28.0f,28.0f};
__device__ __constant__ int   c_ROWOFF[6] = {0,1,3,6,10,15};

__device__ __forceinline__ float sp_f(float z){ return fmaxf(z,0.0f) + log1pf(expf(-fabsf(z))); }
__device__ __forceinline__ float sig_f(float z){ return 1.0f/(1.0f+expf(-z)); }

__device__ __forceinline__ float4 f4all(float v){ return make_float4(v,v,v,v); }
__device__ __forceinline__ void fma4(float4& acc, float w, float4 a){
  acc.x=fmaf(w,a.x,acc.x); acc.y=fmaf(w,a.y,acc.y); acc.z=fmaf(w,a.z,acc.z); acc.w=fmaf(w,a.w,acc.w);
}
__device__ __forceinline__ float4 sp4(float4 z){
  return make_float4(sp_f(z.x),sp_f(z.y),sp_f(z.z),sp_f(z.w));
}
__device__ __forceinline__ float4 sig4(float4 z){
  return make_float4(sig_f(z.x),sig_f(z.y),sig_f(z.z),sig_f(z.w));
}

// XOR-swizzled accessors for sh_t [12][16] (r3/r4-verified conflict-free)
__device__ __forceinline__ const float4* chunkc(const float (*arr)[16], int n, int cc){
  return reinterpret_cast<const float4*>(&arr[n][4*(cc ^ ((n>>1)&3))]);
}
__device__ __forceinline__ float& el(float (*arr)[16], int n, int s){
  return arr[n][4*((s>>2) ^ ((n>>1)&3)) + (s&3)];
}

// ---- MFMA helpers --------------------------------------------------------
__device__ __forceinline__ f32x4 mfma3(half8_t ah, half8_t al, half8_t bh, half8_t bl, f32x4 acc){
  acc = __builtin_amdgcn_mfma_f32_16x16x32_f16(ah, bh, acc, 0,0,0);
  acc = __builtin_amdgcn_mfma_f32_16x16x32_f16(ah, bl, acc, 0,0,0);
  acc = __builtin_amdgcn_mfma_f32_16x16x32_f16(al, bh, acc, 0,0,0);
  return acc;
}
// B-fragment load: B[k][n] fp16 stored [n][136]; lane(quad,n): k = q*32+quad*8..+7
__device__ __forceinline__ half8_t ldB(const _Float16 (*B)[136], int n, int q, int quad){
  return *reinterpret_cast<const half8_t*>(&B[n][q*32 + quad*8]);
}
// store 4-row f32 tile-result as hi/lo fp16 at B[n][base..base+3]
__device__ __forceinline__ void stB4(_Float16 (*Bh)[136], _Float16 (*Bl)[136], int n, int base, float4 v){
  half4_t hi, lo;
  const float* p = &v.x;
  #pragma unroll
  for (int j=0;j<4;j++){ hi[j] = (_Float16)p[j]; lo[j] = (_Float16)(p[j] - (float)hi[j]); }
  *reinterpret_cast<half4_t*>(&Bh[n][base]) = hi;
  *reinterpret_cast<half4_t*>(&Bl[n][base]) = lo;
}
// store row-pair (k2, k2+1) for one sample as hi/lo
__device__ __forceinline__ void stB2(_Float16 (*Bh)[136], _Float16 (*Bl)[136], int n, int k2, float a, float b){
  half2_t hi, lo;
  hi[0]=(_Float16)a; hi[1]=(_Float16)b;
  lo[0]=(_Float16)(a-(float)hi[0]); lo[1]=(_Float16)(b-(float)hi[1]);
  *reinterpret_cast<half2_t*>(&Bh[n][k2]) = hi;
  *reinterpret_cast<half2_t*>(&Bl[n][k2]) = lo;
}

// ---------------- init: transposes + split-fp16 A-fragments ----------------
// frag regions (in halves): W2L @0 (16384), W2V @16384, W2V^T @32768, W3L @49152 (4096)
__global__ void __launch_bounds__(256) k_init(
    const float* __restrict__ W1L, const float* __restrict__ W2L,
    const float* __restrict__ W3L, const float* __restrict__ W1V,
    const float* __restrict__ W2V, const float* __restrict__ b3L,
    float* __restrict__ W1LT, float* __restrict__ W1VT, float* __restrict__ b3Lp,
    _Float16* __restrict__ fragHi, _Float16* __restrict__ fragLo, int* __restrict__ viol)
{
  int t = blockIdx.x*256 + threadIdx.x;
  if (t < 4) viol[t] = 0;
  if (t < 1536){ int i = t/128, k = t%128; W1LT[t] = W1L[k*12+i]; W1VT[t] = W1V[k*12+i]; }
  if (t < 32) b3Lp[t] = (t < 21) ? b3L[t] : 0.0f;
  if (t < 6656){
    int kind, f;
    if (t < 2048){ kind=0; f=t; }
    else if (t < 4096){ kind=1; f=t-2048; }
    else if (t < 6144){ kind=2; f=t-4096; }
    else { kind=3; f=t-6144; }
    int tile = f>>8, q = (f>>6)&3, l = f&63, m = l&15, kq = 8*(l>>4);
    int off = (kind==0?0:kind==1?16384:kind==2?32768:49152) + f*8;
    #pragma unroll
    for (int e=0;e<8;e++){
      float v;
      int kk = 32*q + kq + e;
      if (kind==0)      v = W2L[(16*tile+m)*128 + kk];
      else if (kind==1) v = W2V[(16*tile+m)*128 + kk];
      else if (kind==2) v = W2V[kk*128 + (16*tile+m)];
      else { int r = 16*tile+m; v = (r<21) ? W3L[r*128 + kk] : 0.0f; }
      _Float16 hi = (_Float16)v;
      _Float16 lo = (_Float16)(v - (float)hi);
      fragHi[off+e] = hi; fragLo[off+e] = lo;
    }
  }
}

// ---------------- per-stage state + batch viol reduction ----------------
__global__ void __launch_bounds__(256) k_pre(int stage,
    const float* __restrict__ obs, const float* __restrict__ kqd,
    float* __restrict__ q_cur, float* __restrict__ qd_cur, int* __restrict__ viol)
{
  int b = blockIdx.x*256 + threadIdx.x;
  if (b >= BATCH) return;
  const float* o = obs + b*12;
  unsigned mask = 0;
  #pragma unroll
  for (int i=0;i<6;i++){
    float q0 = o[i], qd0 = o[6+i];
    float q, qd;
    if (stage == 0){ q=q0; qd=qd0; }
    else if (stage == 1){
      q  = q0 + 0.5f*DT*qd0;
      qd = qd0 + 0.5f*DT*kqd[b*6+i];
    } else if (stage == 2){
      q  = q0 + 0.5f*DT*qd0 + 0.25f*DT*DT*kqd[b*6+i];
      qd = qd0 + 0.5f*DT*kqd[B6 + b*6+i];
    } else {
      q  = q0 + DT*qd0 + 0.5f*DT*DT*kqd[B6 + b*6+i];
      qd = qd0 + DT*kqd[2*B6 + b*6+i];
    }
    q_cur[b*6+i]=q; qd_cur[b*6+i]=qd;
    float lo = c_LOWER[i]+0.1f, up = c_UPPER[i]-0.1f;
    if (q <= lo || q >= up) mask |= (1u<<i);
  }
  unsigned wm = 0;
  #pragma unroll
  for (int i=0;i<6;i++) if (__ballot((int)((mask>>i)&1u))) wm |= (1u<<i);
  if ((threadIdx.x & 63)==0 && wm) atomicOr(viol + stage, (int)wm);
}

// ---------------- heavy per-stage accel (MFMA) ----------------
// 16 samples/block, 256 threads (4 waves), 1024 blocks.
// MFMA passes: wave w owns out-row tiles {w, w+4}; all 16 samples in B (N=16).
// VALU phases (L1, dh1-build): lane l owns rows {2l,2l+1}, wave w = samples 4w..4w+3.
__global__ void __launch_bounds__(256) k_accel(
    const float* __restrict__ q_cur, const float* __restrict__ qd_cur,
    const float* __restrict__ action,
    const float* __restrict__ W1LT, const float* __restrict__ b1L,
    const float* __restrict__ b2L,  const float* __restrict__ b3Lp,
    const float* __restrict__ W1VT, const float* __restrict__ b1V,
    const float* __restrict__ b2V,  const float* __restrict__ W3V,
    const float* __restrict__ W1V,
    const _Float16* __restrict__ fragHi, const _Float16* __restrict__ fragLo,
    const int* __restrict__ viol_stage,
    float* __restrict__ kqd_out)
{
  __shared__ alignas(16) _Float16 Bact[2][16][136];   // [hi/lo][n][k] current activation
  __shared__ alignas(16) _Float16 Bd[2][2][16][136];  // [dir][hi/lo][n][k] tangent bufs
  __shared__ alignas(16) float sh_t[12][16];
  __shared__ float sh_y[21][17], sh_s3[21][17], sh_dy[42][17], sh_dv[12][17];
  __shared__ float sh_wg[2][6][16];
  __shared__ float sh_qd[6][16], sh_tau[6][16], sh_f[6][16];
  __shared__ float sh_c[6][16], sh_grav[6][16], sh_v[6][16];

  const int tid = threadIdx.x;
  const int l = tid & 63;
  const int w = tid >> 6;          // wave: MFMA tiles {w, w+4}; VALU sample chunk
  const int lane_n = l & 15;
  const int quad = l >> 4;
  const int base0 = w*16 + quad*4;
  const int base1 = (w+4)*16 + quad*4;
  const int s0 = blockIdx.x * 16;
  const int vm = *viol_stage;

  const half8_t* fW2Lh  = (const half8_t*)(fragHi);
  const half8_t* fW2Ll  = (const half8_t*)(fragLo);
  const half8_t* fW2Vh  = (const half8_t*)(fragHi + 16384);
  const half8_t* fW2Vl  = (const half8_t*)(fragLo + 16384);
  const half8_t* fW2VTh = (const half8_t*)(fragHi + 32768);
  const half8_t* fW2VTl = (const half8_t*)(fragLo + 32768);
  const half8_t* fW3h   = (const half8_t*)(fragHi + 49152);
  const half8_t* fW3l   = (const half8_t*)(fragLo + 49152);

  // ---- phase 0: tile load, trig, tau, constraint force
  if (tid < 96){
    int s = tid & 15, i = tid >> 4;
    float q  = q_cur [(s0+s)*6 + i];
    float qd = qd_cur[(s0+s)*6 + i];
    sh_qd[i][s]=qd;
    sh_tau[i][s] = action[(s0+s)*6+i] * c_EFFORT[i];
    el(sh_t, 2*i,   s) = cosf(q);
    el(sh_t, 2*i+1, s) = sinf(q);
    float lo = c_LOWER[i]+0.1f, up = c_UPPER[i]-0.1f;
    float barrier = -5.0f*(1.0f/(q-lo) - 1.0f/(up-q));
    float clip = (q<=lo)? c_EFFORT[i] : ((q>=up)? -c_EFFORT[i] : 0.0f);
    sh_f[i][s] = ((vm>>i)&1) ? clip : barrier;
    sh_c[i][s] = 0.0f;
  }
  __syncthreads();

  float4 s1a, s1b;   // sigmoid(z1) rows 2l,2l+1 x samples 4w..+3
  // ---- L1L (VALU) -> Bact
  {
    float2 bb = *reinterpret_cast<const float2*>(b1L + 2*l);
    float4 z0 = f4all(bb.x), z1 = f4all(bb.y);
    #pragma unroll
    for (int i=0;i<12;i++){
      float2 wv = *reinterpret_cast<const float2*>(W1LT + i*128 + 2*l);
      float4 a = *chunkc(sh_t, i, w);
      fma4(z0, wv.x, a); fma4(z1, wv.y, a);
    }
    float4 h0 = sp4(z0), h1 = sp4(z1);
    s1a = sig4(z0); s1b = sig4(z1);
    #pragma unroll
    for (int j=0;j<4;j++)
      stB2(Bact[0], Bact[1], 4*w+j, 2*l, (&h0.x)[j], (&h1.x)[j]);
  }
  __syncthreads();

  float4 s2a, s2b;   // sigmoid(z2) rows base0..+3 / base1..+3, col lane_n
  // ---- L2L MFMA + epilogue (h2 -> Bact in-place)
  {
    f32x4 acc0 = {0.f,0.f,0.f,0.f}, acc1 = {0.f,0.f,0.f,0.f};
    #pragma unroll
    for (int q=0;q<4;q++){
      half8_t bh = ldB(Bact[0], lane_n, q, quad);
      half8_t bl = ldB(Bact[1], lane_n, q, quad);
      acc0 = mfma3(fW2Lh[(w*4+q)*64+l],     fW2Ll[(w*4+q)*64+l],     bh, bl, acc0);
      acc1 = mfma3(fW2Lh[((w+4)*4+q)*64+l], fW2Ll[((w+4)*4+q)*64+l], bh, bl, acc1);
    }
    __syncthreads();   // all h1 reads done before overwrite
    float4 ba = *reinterpret_cast<const float4*>(b2L + base0);
    float4 bb = *reinterpret_cast<const float4*>(b2L + base1);
    float4 h2a, h2b;
    #pragma unroll
    for (int j=0;j<4;j++){
      float z = acc0[j] + (&ba.x)[j];
      (&h2a.x)[j] = sp_f(z); (&s2a.x)[j] = sig_f(z);
      z = acc1[j] + (&bb.x)[j];
      (&h2b.x)[j] = sp_f(z); (&s2b.x)[j] = sig_f(z);
    }
    stB4(Bact[0], Bact[1], lane_n, base0, h2a);
    stB4(Bact[0], Bact[1], lane_n, base1, h2b);
  }
  __syncthreads();

  // ---- L3 MFMA (waves 0,1) -> y, s3 (f32)
  if (w < 2){
    f32x4 acc = {0.f,0.f,0.f,0.f};
    #pragma unroll
    for (int q=0;q<4;q++){
      half8_t bh = ldB(Bact[0], lane_n, q, quad);
      half8_t bl = ldB(Bact[1], lane_n, q, quad);
      acc = mfma3(fW3h[(w*4+q)*64+l], fW3l[(w*4+q)*64+l], bh, bl, acc);
    }
    int rb = w*16 + quad*4;
    #pragma unroll
    for (int j=0;j<4;j++){
      int r = rb + j;
      if (r < 21){
        float z = acc[j] + b3Lp[r];
        sh_y[r][lane_n]  = sp_f(z);
        sh_s3[r][lane_n] = sig_f(z);
      }
    }
  }
  __syncthreads();

  // ---- v = L^T qdot
  if (tid < 96){
    int s = tid & 15, jj = tid >> 4;
    float acc = 0.f;
    for (int i=jj;i<6;i++) acc = fmaf(sh_y[c_ROWOFF[i]+jj][s], sh_qd[i][s], acc);
    sh_v[jj][s] = acc;
  }
  // (no sync needed: dh1 build below touches different arrays; barrier follows)

  // ---- tangent groups: dirs {2G, 2G+1}
  for (int G=0; G<3; ++G){
    // dh1 build (VALU) -> Bd[0], Bd[1]
    #pragma unroll
    for (int d=0; d<2; ++d){
      int g = 2*G + d;
      float2 w0 = *reinterpret_cast<const float2*>(W1LT + (2*g)*128 + 2*l);
      float2 w1 = *reinterpret_cast<const float2*>(W1LT + (2*g+1)*128 + 2*l);
      float4 tc = *chunkc(sh_t, 2*g,   w);
      float4 ts = *chunkc(sh_t, 2*g+1, w);
      #pragma unroll
      for (int j=0;j<4;j++){
        float tcj = (&tc.x)[j], tsj = (&ts.x)[j];
        float d0 = (&s1a.x)[j]*(tcj*w1.x - tsj*w0.x);
        float d1 = (&s1b.x)[j]*(tcj*w1.y - tsj*w0.y);
        stB2(Bd[d][0], Bd[d][1], 4*w+j, 2*l, d0, d1);
      }
    }
    __syncthreads();
    // fused W2 tangent MFMA: acc[tile][dir]
    f32x4 ta00={0.f,0.f,0.f,0.f}, ta01=ta00, ta10=ta00, ta11=ta00;
    #pragma unroll
    for (int q=0;q<4;q++){
      half8_t b0h = ldB(Bd[0][0], lane_n, q, quad);
      half8_t b0l = ldB(Bd[0][1], lane_n, q, quad);
      half8_t b1h = ldB(Bd[1][0], lane_n, q, quad);
      half8_t b1l = ldB(Bd[1][1], lane_n, q, quad);
      half8_t a0h = fW2Lh[(w*4+q)*64+l],     a0l = fW2Ll[(w*4+q)*64+l];
      half8_t a1h = fW2Lh[((w+4)*4+q)*64+l], a1l = fW2Ll[((w+4)*4+q)*64+l];
      ta00 = mfma3(a0h, a0l, b0h, b0l, ta00);
      ta01 = mfma3(a0h, a0l, b1h, b1l, ta01);
      ta10 = mfma3(a1h, a1l, b0h, b0l, ta10);
      ta11 = mfma3(a1h, a1l, b1h, b1l, ta11);
    }
    __syncthreads();   // all dh1 reads done before overwrite
    // dh2 = s2 ⊙ acc -> Bd in-place
    {
      float4 v;
      #pragma unroll
      for (int j=0;j<4;j++) (&v.x)[j] = (&s2a.x)[j]*ta00[j];
      stB4(Bd[0][0], Bd[0][1], lane_n, base0, v);
      #pragma unroll
      for (int j=0;j<4;j++) (&v.x)[j] = (&s2b.x)[j]*ta10[j];
      stB4(Bd[0][0], Bd[0][1], lane_n, base1, v);
      #pragma unroll
      for (int j=0;j<4;j++) (&v.x)[j] = (&s2a.x)[j]*ta01[j];
      stB4(Bd[1][0], Bd[1][1], lane_n, base0, v);
      #pragma unroll
      for (int j=0;j<4;j++) (&v.x)[j] = (&s2b.x)[j]*ta11[j];
      stB4(Bd[1][0], Bd[1][1], lane_n, base1, v);
    }
    __syncthreads();
    // dy MFMA: wave job (d = w&1, tile tt = w>>1)
    {
      int d = w & 1, tt = w >> 1;
      f32x4 acc = {0.f,0.f,0.f,0.f};
      #pragma unroll
      for (int q=0;q<4;q++){
        half8_t bh = ldB(Bd[d][0], lane_n, q, quad);
        half8_t bl = ldB(Bd[d][1], lane_n, q, quad);
        acc = mfma3(fW3h[(tt*4+q)*64+l], fW3l[(tt*4+q)*64+l], bh, bl, acc);
      }
      int rb = tt*16 + quad*4;
      #pragma unroll
      for (int j=0;j<4;j++){
        int r = rb + j;
        if (r < 21) sh_dy[d*21 + r][lane_n] = sh_s3[r][lane_n] * acc[j];
      }
    }
    __syncthreads();
    // Coriolis phase A: 32 threads (gg, s)
    if (tid < 32){
      int s = tid & 15, gg = tid >> 4;
      float qd[6];
      #pragma unroll
      for (int i=0;i<6;i++) qd[i] = sh_qd[i][s];
      float u[6];
      #pragma unroll
      for (int jj=0;jj<6;jj++){
        float acc = 0.f;
        for (int i=jj;i<6;i++) acc = fmaf(sh_dy[gg*21 + c_ROWOFF[i]+jj][s], qd[i], acc);
        u[jj] = acc;
      }
      #pragma unroll
      for (int i=0;i<6;i++){
        float acc = 0.f;
        for (int j=0;j<=i;j++){
          acc = fmaf(sh_dy[gg*21 + c_ROWOFF[i]+j][s], sh_v[j][s], acc);
          acc = fmaf(sh_y [c_ROWOFF[i]+j][s], u[j], acc);
        }
        sh_wg[gg][i][s] = acc;
      }
    }
    __syncthreads();
    // Coriolis phase B: 96 threads (i, s)
    if (tid < 96){
      int s = tid & 15, i = tid >> 4;
      float acc = sh_c[i][s];
      acc = fmaf(sh_qd[2*G][s],   sh_wg[0][i][s], acc);
      acc = fmaf(sh_qd[2*G+1][s], sh_wg[1][i][s], acc);
      int gi = i - 2*G;
      if (gi == 0 || gi == 1){
        float r = 0.f;
        #pragma unroll
        for (int j=0;j<6;j++) r = fmaf(sh_qd[j][s], sh_wg[gi][j][s], r);
        acc -= 0.5f*r;
      }
      sh_c[i][s] = acc;
    }
    __syncthreads();
  }

  // ---- V-net L1 (VALU) -> Bact (h2 dead)
  {
    float2 bb = *reinterpret_cast<const float2*>(b1V + 2*l);
    float4 z0 = f4all(bb.x), z1 = f4all(bb.y);
    #pragma unroll
    for (int i=0;i<12;i++){
      float2 wv = *reinterpret_cast<const float2*>(W1VT + i*128 + 2*l);
      float4 a = *chunkc(sh_t, i, w);
      fma4(z0, wv.x, a); fma4(z1, wv.y, a);
    }
    float4 h0 = sp4(z0), h1 = sp4(z1);
    #pragma unroll
    for (int j=0;j<4;j++)
      stB2(Bact[0], Bact[1], 4*w+j, 2*l, (&h0.x)[j], (&h1.x)[j]);
  }
  __syncthreads();
  // ---- L2V MFMA; epilogue g2 = sig(z)*W3V -> Bact in-place
  {
    f32x4 acc0 = {0.f,0.f,0.f,0.f}, acc1 = {0.f,0.f,0.f,0.f};
    #pragma unroll
    for (int q=0;q<4;q++){
      half8_t bh = ldB(Bact[0], lane_n, q, quad);
      half8_t bl = ldB(Bact[1], lane_n, q, quad);
      acc0 = mfma3(fW2Vh[(w*4+q)*64+l],     fW2Vl[(w*4+q)*64+l],     bh, bl, acc0);
      acc1 = mfma3(fW2Vh[((w+4)*4+q)*64+l], fW2Vl[((w+4)*4+q)*64+l], bh, bl, acc1);
    }
    __syncthreads();
    float4 ba  = *reinterpret_cast<const float4*>(b2V + base0);
    float4 bb  = *reinterpret_cast<const float4*>(b2V + base1);
    float4 w3a = *reinterpret_cast<const float4*>(W3V + base0);
    float4 w3b = *reinterpret_cast<const float4*>(W3V + base1);
    float4 g2a, g2b;
    #pragma unroll
    for (int j=0;j<4;j++){
      (&g2a.x)[j] = sig_f(acc0[j] + (&ba.x)[j]) * (&w3a.x)[j];
      (&g2b.x)[j] = sig_f(acc1[j] + (&bb.x)[j]) * (&w3b.x)[j];
    }
    stB4(Bact[0], Bact[1], lane_n, base0, g2a);
    stB4(Bact[0], Bact[1], lane_n, base1, g2b);
  }
  __syncthreads();
  // ---- V bwd MFMA (A = W2V^T); epilogue: recompute s1V, g1 -> f32 overlay on Bd[1]
  float* g1p = reinterpret_cast<float*>(&Bd[1][0][0][0]);   // [128][17] f32 (8704 B fits exactly)
  {
    f32x4 acc0 = {0.f,0.f,0.f,0.f}, acc1 = {0.f,0.f,0.f,0.f};
    #pragma unroll
    for (int q=0;q<4;q++){
      half8_t bh = ldB(Bact[0], lane_n, q, quad);
      half8_t bl = ldB(Bact[1], lane_n, q, quad);
      acc0 = mfma3(fW2VTh[(w*4+q)*64+l],     fW2VTl[(w*4+q)*64+l],     bh, bl, acc0);
      acc1 = mfma3(fW2VTh[((w+4)*4+q)*64+l], fW2VTl[((w+4)*4+q)*64+l], bh, bl, acc1);
    }
    float tn[12];
    #pragma unroll
    for (int i=0;i<12;i++) tn[i] = el(sh_t, i, lane_n);
    #pragma unroll
    for (int j=0;j<4;j++){
      int r = base0 + j;
      float z = b1V[r];
      const float* wr = W1V + r*12;
      #pragma unroll
      for (int i=0;i<12;i++) z = fmaf(wr[i], tn[i], z);
      g1p[r*17 + lane_n] = sig_f(z) * acc0[j];
      r = base1 + j;
      z = b1V[r];
      wr = W1V + r*12;
      #pragma unroll
      for (int i=0;i<12;i++) z = fmaf(wr[i], tn[i], z);
      g1p[r*17 + lane_n] = sig_f(z) * acc1[j];
    }
  }
  __syncthreads();
  // ---- dV/dt = W1V^T g1 (12 x 16)
  if (tid < 192){
    int i = tid >> 4, n = tid & 15;
    float acc = 0.f;
    for (int j=0;j<128;j++) acc = fmaf(W1V[j*12+i], g1p[j*17+n], acc);
    sh_dv[i][n] = acc;
  }
  __syncthreads();
  // ---- gravity
  if (tid < 96){
    int k = tid>>4, s = tid&15;
    sh_grav[k][s] = fmaf(el(sh_t,2*k,s), sh_dv[2*k+1][s],
                         -(el(sh_t,2*k+1,s)*sh_dv[2*k][s]));
  }
  __syncthreads();
  // ---- assembly: two triangular solves with L (M = L L^T); 4 samples/wave
  if (l < 4){
    int s = w*4 + l;
    float Lm[21];
    #pragma unroll
    for (int o=0;o<21;o++) Lm[o] = sh_y[o][s];
    float rhs[6];
    #pragma unroll
    for (int i=0;i<6;i++) rhs[i] = sh_tau[i][s] - sh_c[i][s] - sh_grav[i][s] - sh_f[i][s];
    float z[6];
    #pragma unroll
    for (int i=0;i<6;i++){
      float acc = rhs[i];
      for (int j=0;j<i;j++) acc = fmaf(-Lm[c_ROWOFF[i]+j], z[j], acc);
      z[i] = acc / Lm[c_ROWOFF[i]+i];
    }
    float a[6];
    #pragma unroll
    for (int i=5;i>=0;i--){
      float acc = z[i];
      for (int j=i+1;j<6;j++) acc = fmaf(-Lm[c_ROWOFF[j]+i], a[j], acc);
      a[i] = acc / Lm[c_ROWOFF[i]+i];
    }
    #pragma unroll
    for (int i=0;i<6;i++) kqd_out[(s0+s)*6+i] = a[i];
  }
}

// ---------------- final RK4 combine ----------------
__global__ void __launch_bounds__(256) k_final(const float* __restrict__ obs,
    const float* __restrict__ kqd, float* __restrict__ out)
{
  int b = blockIdx.x*256 + threadIdx.x;
  if (b >= BATCH) return;
  const float* o = obs + b*12;
  float* po = out + b*12;
  #pragma unroll
  for (int i=0;i<6;i++){
    float q0=o[i], qd0=o[6+i];
    float k1=kqd[b*6+i], k2=kqd[B6+b*6+i], k3=kqd[2*B6+b*6+i], k4=kqd[3*B6+b*6+i];
    float qn = q0 + DT*qd0 + (DT*DT/6.0f)*(k1+k2+k3);
    qn = fminf(fmaxf(qn, c_LOWER[i]), c_UPPER[i]);
    po[i] = qn;
    po[6+i] = qd0 + (DT/6.0f)*(k1 + 2.0f*k2 + 2.0f*k3 + k4);
  }
}

extern "C" void kernel_launch(void* const* d_in, const int* in_sizes, int n_in,
                              void* d_out, int out_size, void* d_ws, size_t ws_size,
                              hipStream_t stream) {
  const float* obs    = (const float*)d_in[0];
  const float* action = (const float*)d_in[1];
  const float* W1L = (const float*)d_in[2];  const float* b1L = (const float*)d_in[3];
  const float* W2L = (const float*)d_in[4];  const float* b2L = (const float*)d_in[5];
  const float* W3L = (const float*)d_in[6];  const float* b3L = (const float*)d_in[7];
  const float* W1V = (const float*)d_in[8];  const float* b1V = (const float*)d_in[9];
  const float* W2V = (const float*)d_in[10]; const float* b2V = (const float*)d_in[11];
  const float* W3V = (const float*)d_in[12]; // b3V unused: only grad of V needed

  float* ws = (float*)d_ws;
  _Float16* fragHi = (_Float16*)ws;            // 53248 halves
  _Float16* fragLo = fragHi + 53248;           // 53248 halves  (total 53248 floats)
  float* W1LT  = ws + 53248;                   // 1536
  float* W1VT  = W1LT + 1536;                  // 1536
  float* b3Lp  = W1VT + 1536;                  // 32
  float* q_cur  = b3Lp + 32;                   // B6
  float* qd_cur = q_cur + B6;                  // B6
  float* kqd    = qd_cur + B6;                 // 4*B6
  int*   viol   = (int*)(kqd + 4*B6);

  float* out = (float*)d_out;

  k_init<<<64,256,0,stream>>>(W1L, W2L, W3L, W1V, W2V, b3L,
                              W1LT, W1VT, b3Lp, fragHi, fragLo, viol);
  for (int s=0; s<4; ++s){
    k_pre<<<64,256,0,stream>>>(s, obs, kqd, q_cur, qd_cur, viol);
    k_accel<<<1024,256,0,stream>>>(q_cur, qd_cur, action,
        W1LT, b1L, b2L, b3Lp, W1VT, b1V, b2V, W3V, W1V,
        fragHi, fragLo, viol + s, kqd + s*B6);
  }
  k_final<<<64,256,0,stream>>>(obs, kqd, out);
}

// Round 7
// 266.426 us; speedup vs baseline: 4.0526x; 1.3239x over previous
//
#include <hip/hip_runtime.h>
#include <math.h>

#define BATCH 16384
#define B6 (BATCH*6)
#define DT 0.01f

using half8_t = __attribute__((ext_vector_type(8))) _Float16;
using half4_t = __attribute__((ext_vector_type(4))) _Float16;
using half2_t = __attribute__((ext_vector_type(2))) _Float16;
using f32x4   = __attribute__((ext_vector_type(4))) float;

__device__ __constant__ float c_LOWER[6]  = {-6.28f,-6.28f,-3.14f,-6.28f,-6.28f,-6.28f};
__device__ __constant__ float c_UPPER[6]  = { 6.28f, 6.28f, 3.14f, 6.28f, 6.28f, 6.28f};
__device__ __constant__ float c_EFFORT[6] = {150.0f,150.0f,150.0f,28.0f,28.0f,28.0f};
__device__ __constant__ int   c_ROWOFF[6] = {0,1,3,6,10,15};

// hardware-native transcendentals: v_exp/v_log/v_rcp (~2^-21 rel err, same
// order as the split-fp16 path's 2^-22 — precision-neutral here)
__device__ __forceinline__ float sp_f(float z){
  return fmaxf(z,0.0f) + __logf(1.0f + __expf(-fabsf(z)));
}
__device__ __forceinline__ float sig_f(float z){
  return __builtin_amdgcn_rcpf(1.0f + __expf(-z));
}

__device__ __forceinline__ float4 f4all(float v){ return make_float4(v,v,v,v); }
__device__ __forceinline__ void fma4(float4& acc, float w, float4 a){
  acc.x=fmaf(w,a.x,acc.x); acc.y=fmaf(w,a.y,acc.y); acc.z=fmaf(w,a.z,acc.z); acc.w=fmaf(w,a.w,acc.w);
}
__device__ __forceinline__ float4 sp4(float4 z){
  return make_float4(sp_f(z.x),sp_f(z.y),sp_f(z.z),sp_f(z.w));
}
__device__ __forceinline__ float4 sig4(float4 z){
  return make_float4(sig_f(z.x),sig_f(z.y),sig_f(z.z),sig_f(z.w));
}

// XOR-swizzled accessors for sh_t [12][16] (r3/r4-verified conflict-free)
__device__ __forceinline__ const float4* chunkc(const float (*arr)[16], int n, int cc){
  return reinterpret_cast<const float4*>(&arr[n][4*(cc ^ ((n>>1)&3))]);
}
__device__ __forceinline__ float& el(float (*arr)[16], int n, int s){
  return arr[n][4*((s>>2) ^ ((n>>1)&3)) + (s&3)];
}

// ---- MFMA helpers --------------------------------------------------------
__device__ __forceinline__ f32x4 mfma3(half8_t ah, half8_t al, half8_t bh, half8_t bl, f32x4 acc){
  acc = __builtin_amdgcn_mfma_f32_16x16x32_f16(ah, bh, acc, 0,0,0);
  acc = __builtin_amdgcn_mfma_f32_16x16x32_f16(ah, bl, acc, 0,0,0);
  acc = __builtin_amdgcn_mfma_f32_16x16x32_f16(al, bh, acc, 0,0,0);
  return acc;
}
__device__ __forceinline__ half8_t ldB(const _Float16 (*B)[136], int n, int q, int quad){
  return *reinterpret_cast<const half8_t*>(&B[n][q*32 + quad*8]);
}
__device__ __forceinline__ void stB4(_Float16 (*Bh)[136], _Float16 (*Bl)[136], int n, int base, float4 v){
  half4_t hi, lo;
  const float* p = &v.x;
  #pragma unroll
  for (int j=0;j<4;j++){ hi[j] = (_Float16)p[j]; lo[j] = (_Float16)(p[j] - (float)hi[j]); }
  *reinterpret_cast<half4_t*>(&Bh[n][base]) = hi;
  *reinterpret_cast<half4_t*>(&Bl[n][base]) = lo;
}
__device__ __forceinline__ void stB2(_Float16 (*Bh)[136], _Float16 (*Bl)[136], int n, int k2, float a, float b){
  half2_t hi, lo;
  hi[0]=(_Float16)a; hi[1]=(_Float16)b;
  lo[0]=(_Float16)(a-(float)hi[0]); lo[1]=(_Float16)(b-(float)hi[1]);
  *reinterpret_cast<half2_t*>(&Bh[n][k2]) = hi;
  *reinterpret_cast<half2_t*>(&Bl[n][k2]) = lo;
}

// ---------------- init: transposes + split-fp16 A-fragments ----------------
// frag regions (in halves): W2L @0, W2V @16384, W2V^T @32768, W3L @49152,
// W1V^T @53248 (rows 12..15 zero-padded)
__global__ void __launch_bounds__(256) k_init(
    const float* __restrict__ W1L, const float* __restrict__ W2L,
    const float* __restrict__ W3L, const float* __restrict__ W1V,
    const float* __restrict__ W2V, const float* __restrict__ b3L,
    float* __restrict__ W1LT, float* __restrict__ W1VT, float* __restrict__ b3Lp,
    _Float16* __restrict__ fragHi, _Float16* __restrict__ fragLo, int* __restrict__ viol)
{
  int t = blockIdx.x*256 + threadIdx.x;
  if (t < 4) viol[t] = 0;
  if (t < 1536){ int i = t/128, k = t%128; W1LT[t] = W1L[k*12+i]; W1VT[t] = W1V[k*12+i]; }
  if (t < 32) b3Lp[t] = (t < 21) ? b3L[t] : 0.0f;
  if (t < 6912){
    int kind, f;
    if (t < 2048){ kind=0; f=t; }
    else if (t < 4096){ kind=1; f=t-2048; }
    else if (t < 6144){ kind=2; f=t-4096; }
    else if (t < 6656){ kind=3; f=t-6144; }
    else { kind=4; f=t-6656; }
    int tile = f>>8, q = (f>>6)&3, l = f&63, m = l&15, kq = 8*(l>>4);
    int off = (kind==0?0:kind==1?16384:kind==2?32768:kind==3?49152:53248) + f*8;
    #pragma unroll
    for (int e=0;e<8;e++){
      float v;
      int kk = 32*q + kq + e;
      if (kind==0)      v = W2L[(16*tile+m)*128 + kk];
      else if (kind==1) v = W2V[(16*tile+m)*128 + kk];
      else if (kind==2) v = W2V[kk*128 + (16*tile+m)];
      else if (kind==3){ int r = 16*tile+m; v = (r<21) ? W3L[r*128 + kk] : 0.0f; }
      else              v = (m<12) ? W1V[kk*12 + m] : 0.0f;
      _Float16 hi = (_Float16)v;
      _Float16 lo = (_Float16)(v - (float)hi);
      fragHi[off+e] = hi; fragLo[off+e] = lo;
    }
  }
}

// ---------------- stage-0 state + batch viol reduction ----------------
__global__ void __launch_bounds__(256) k_pre0(
    const float* __restrict__ obs,
    float* __restrict__ q_cur, float* __restrict__ qd_cur, int* __restrict__ viol)
{
  int b = blockIdx.x*256 + threadIdx.x;
  if (b >= BATCH) return;
  const float* o = obs + b*12;
  unsigned mask = 0;
  #pragma unroll
  for (int i=0;i<6;i++){
    float q = o[i];
    q_cur[b*6+i]=q; qd_cur[b*6+i]=o[6+i];
    float lo = c_LOWER[i]+0.1f, up = c_UPPER[i]-0.1f;
    if (q <= lo || q >= up) mask |= (1u<<i);
  }
  unsigned wm = 0;
  #pragma unroll
  for (int i=0;i<6;i++) if (__ballot((int)((mask>>i)&1u))) wm |= (1u<<i);
  if ((threadIdx.x & 63)==0 && wm) atomicOr(viol, (int)wm);
}

// ---------------- heavy per-stage accel (MFMA) ----------------
// 16 samples/block, 256 threads (4 waves), 1024 blocks.
// Tail folds next-stage k_pre (state update + viol ballot) for stages 0..2.
__global__ void __launch_bounds__(256) k_accel(
    int stage,
    const float* __restrict__ obs,
    float* __restrict__ q_cur, float* __restrict__ qd_cur,
    const float* __restrict__ action,
    const float* __restrict__ W1LT, const float* __restrict__ b1L,
    const float* __restrict__ b2L,  const float* __restrict__ b3Lp,
    const float* __restrict__ W1VT, const float* __restrict__ b1V,
    const float* __restrict__ b2V,  const float* __restrict__ W3V,
    const float* __restrict__ W1V,
    const _Float16* __restrict__ fragHi, const _Float16* __restrict__ fragLo,
    int* __restrict__ viol,
    float* __restrict__ kqd_all)
{
  __shared__ alignas(16) _Float16 Bact[2][16][136];
  __shared__ alignas(16) _Float16 Bd[2][2][16][136];
  __shared__ alignas(16) float sh_t[12][16];
  __shared__ float sh_y[21][17], sh_s3[21][17], sh_dy[42][17], sh_dv[12][17];
  __shared__ float sh_wg[2][6][16];
  __shared__ float sh_qd[6][16], sh_tau[6][16], sh_f[6][16];
  __shared__ float sh_c[6][16], sh_grav[6][16], sh_v[6][16];

  const int tid = threadIdx.x;
  const int l = tid & 63;
  const int w = tid >> 6;
  const int lane_n = l & 15;
  const int quad = l >> 4;
  const int base0 = w*16 + quad*4;
  const int base1 = (w+4)*16 + quad*4;
  const int s0 = blockIdx.x * 16;
  const int vm = viol[stage];

  const half8_t* fW2Lh  = (const half8_t*)(fragHi);
  const half8_t* fW2Ll  = (const half8_t*)(fragLo);
  const half8_t* fW2Vh  = (const half8_t*)(fragHi + 16384);
  const half8_t* fW2Vl  = (const half8_t*)(fragLo + 16384);
  const half8_t* fW2VTh = (const half8_t*)(fragHi + 32768);
  const half8_t* fW2VTl = (const half8_t*)(fragLo + 32768);
  const half8_t* fW3h   = (const half8_t*)(fragHi + 49152);
  const half8_t* fW3l   = (const half8_t*)(fragLo + 49152);
  const half8_t* fW1Th  = (const half8_t*)(fragHi + 53248);
  const half8_t* fW1Tl  = (const half8_t*)(fragLo + 53248);

  // ---- phase 0: tile load, trig, tau, constraint force
  if (tid < 96){
    int s = tid & 15, i = tid >> 4;
    float q  = q_cur [(s0+s)*6 + i];
    float qd = qd_cur[(s0+s)*6 + i];
    sh_qd[i][s]=qd;
    sh_tau[i][s] = action[(s0+s)*6+i] * c_EFFORT[i];
    el(sh_t, 2*i,   s) = cosf(q);
    el(sh_t, 2*i+1, s) = sinf(q);
    float lo = c_LOWER[i]+0.1f, up = c_UPPER[i]-0.1f;
    float barrier = -5.0f*(1.0f/(q-lo) - 1.0f/(up-q));
    float clip = (q<=lo)? c_EFFORT[i] : ((q>=up)? -c_EFFORT[i] : 0.0f);
    sh_f[i][s] = ((vm>>i)&1) ? clip : barrier;
    sh_c[i][s] = 0.0f;
  }
  __syncthreads();

  float4 s1a, s1b;
  // ---- L1L (VALU) -> Bact
  {
    float2 bb = *reinterpret_cast<const float2*>(b1L + 2*l);
    float4 z0 = f4all(bb.x), z1 = f4all(bb.y);
    #pragma unroll
    for (int i=0;i<12;i++){
      float2 wv = *reinterpret_cast<const float2*>(W1LT + i*128 + 2*l);
      float4 a = *chunkc(sh_t, i, w);
      fma4(z0, wv.x, a); fma4(z1, wv.y, a);
    }
    float4 h0 = sp4(z0), h1 = sp4(z1);
    s1a = sig4(z0); s1b = sig4(z1);
    #pragma unroll
    for (int j=0;j<4;j++)
      stB2(Bact[0], Bact[1], 4*w+j, 2*l, (&h0.x)[j], (&h1.x)[j]);
  }
  __syncthreads();

  float4 s2a, s2b;
  // ---- L2L MFMA + epilogue (h2 -> Bact in-place)
  {
    f32x4 acc0 = {0.f,0.f,0.f,0.f}, acc1 = {0.f,0.f,0.f,0.f};
    #pragma unroll
    for (int q=0;q<4;q++){
      half8_t bh = ldB(Bact[0], lane_n, q, quad);
      half8_t bl = ldB(Bact[1], lane_n, q, quad);
      acc0 = mfma3(fW2Lh[(w*4+q)*64+l],     fW2Ll[(w*4+q)*64+l],     bh, bl, acc0);
      acc1 = mfma3(fW2Lh[((w+4)*4+q)*64+l], fW2Ll[((w+4)*4+q)*64+l], bh, bl, acc1);
    }
    __syncthreads();
    float4 ba = *reinterpret_cast<const float4*>(b2L + base0);
    float4 bb = *reinterpret_cast<const float4*>(b2L + base1);
    float4 h2a, h2b;
    #pragma unroll
    for (int j=0;j<4;j++){
      float z = acc0[j] + (&ba.x)[j];
      (&h2a.x)[j] = sp_f(z); (&s2a.x)[j] = sig_f(z);
      z = acc1[j] + (&bb.x)[j];
      (&h2b.x)[j] = sp_f(z); (&s2b.x)[j] = sig_f(z);
    }
    stB4(Bact[0], Bact[1], lane_n, base0, h2a);
    stB4(Bact[0], Bact[1], lane_n, base1, h2b);
  }
  __syncthreads();

  // ---- L3 MFMA (waves 0,1) -> y, s3
  if (w < 2){
    f32x4 acc = {0.f,0.f,0.f,0.f};
    #pragma unroll
    for (int q=0;q<4;q++){
      half8_t bh = ldB(Bact[0], lane_n, q, quad);
      half8_t bl = ldB(Bact[1], lane_n, q, quad);
      acc = mfma3(fW3h[(w*4+q)*64+l], fW3l[(w*4+q)*64+l], bh, bl, acc);
    }
    int rb = w*16 + quad*4;
    #pragma unroll
    for (int j=0;j<4;j++){
      int r = rb + j;
      if (r < 21){
        float z = acc[j] + b3Lp[r];
        sh_y[r][lane_n]  = sp_f(z);
        sh_s3[r][lane_n] = sig_f(z);
      }
    }
  }
  __syncthreads();

  // ---- v = L^T qdot
  if (tid < 96){
    int s = tid & 15, jj = tid >> 4;
    float acc = 0.f;
    for (int i=jj;i<6;i++) acc = fmaf(sh_y[c_ROWOFF[i]+jj][s], sh_qd[i][s], acc);
    sh_v[jj][s] = acc;
  }

  // ---- tangent groups: dirs {2G, 2G+1}
  for (int G=0; G<3; ++G){
    #pragma unroll
    for (int d=0; d<2; ++d){
      int g = 2*G + d;
      float2 w0 = *reinterpret_cast<const float2*>(W1LT + (2*g)*128 + 2*l);
      float2 w1 = *reinterpret_cast<const float2*>(W1LT + (2*g+1)*128 + 2*l);
      float4 tc = *chunkc(sh_t, 2*g,   w);
      float4 ts = *chunkc(sh_t, 2*g+1, w);
      #pragma unroll
      for (int j=0;j<4;j++){
        float tcj = (&tc.x)[j], tsj = (&ts.x)[j];
        float d0 = (&s1a.x)[j]*(tcj*w1.x - tsj*w0.x);
        float d1 = (&s1b.x)[j]*(tcj*w1.y - tsj*w0.y);
        stB2(Bd[d][0], Bd[d][1], 4*w+j, 2*l, d0, d1);
      }
    }
    __syncthreads();
    f32x4 ta00={0.f,0.f,0.f,0.f}, ta01=ta00, ta10=ta00, ta11=ta00;
    #pragma unroll
    for (int q=0;q<4;q++){
      half8_t b0h = ldB(Bd[0][0], lane_n, q, quad);
      half8_t b0l = ldB(Bd[0][1], lane_n, q, quad);
      half8_t b1h = ldB(Bd[1][0], lane_n, q, quad);
      half8_t b1l = ldB(Bd[1][1], lane_n, q, quad);
      half8_t a0h = fW2Lh[(w*4+q)*64+l],     a0l = fW2Ll[(w*4+q)*64+l];
      half8_t a1h = fW2Lh[((w+4)*4+q)*64+l], a1l = fW2Ll[((w+4)*4+q)*64+l];
      ta00 = mfma3(a0h, a0l, b0h, b0l, ta00);
      ta01 = mfma3(a0h, a0l, b1h, b1l, ta01);
      ta10 = mfma3(a1h, a1l, b0h, b0l, ta10);
      ta11 = mfma3(a1h, a1l, b1h, b1l, ta11);
    }
    __syncthreads();
    {
      float4 v;
      #pragma unroll
      for (int j=0;j<4;j++) (&v.x)[j] = (&s2a.x)[j]*ta00[j];
      stB4(Bd[0][0], Bd[0][1], lane_n, base0, v);
      #pragma unroll
      for (int j=0;j<4;j++) (&v.x)[j] = (&s2b.x)[j]*ta10[j];
      stB4(Bd[0][0], Bd[0][1], lane_n, base1, v);
      #pragma unroll
      for (int j=0;j<4;j++) (&v.x)[j] = (&s2a.x)[j]*ta01[j];
      stB4(Bd[1][0], Bd[1][1], lane_n, base0, v);
      #pragma unroll
      for (int j=0;j<4;j++) (&v.x)[j] = (&s2b.x)[j]*ta11[j];
      stB4(Bd[1][0], Bd[1][1], lane_n, base1, v);
    }
    __syncthreads();
    {
      int d = w & 1, tt = w >> 1;
      f32x4 acc = {0.f,0.f,0.f,0.f};
      #pragma unroll
      for (int q=0;q<4;q++){
        half8_t bh = ldB(Bd[d][0], lane_n, q, quad);
        half8_t bl = ldB(Bd[d][1], lane_n, q, quad);
        acc = mfma3(fW3h[(tt*4+q)*64+l], fW3l[(tt*4+q)*64+l], bh, bl, acc);
      }
      int rb = tt*16 + quad*4;
      #pragma unroll
      for (int j=0;j<4;j++){
        int r = rb + j;
        if (r < 21) sh_dy[d*21 + r][lane_n] = sh_s3[r][lane_n] * acc[j];
      }
    }
    __syncthreads();
    if (tid < 32){
      int s = tid & 15, gg = tid >> 4;
      float qd[6];
      #pragma unroll
      for (int i=0;i<6;i++) qd[i] = sh_qd[i][s];
      float u[6];
      #pragma unroll
      for (int jj=0;jj<6;jj++){
        float acc = 0.f;
        for (int i=jj;i<6;i++) acc = fmaf(sh_dy[gg*21 + c_ROWOFF[i]+jj][s], qd[i], acc);
        u[jj] = acc;
      }
      #pragma unroll
      for (int i=0;i<6;i++){
        float acc = 0.f;
        for (int j=0;j<=i;j++){
          acc = fmaf(sh_dy[gg*21 + c_ROWOFF[i]+j][s], sh_v[j][s], acc);
          acc = fmaf(sh_y [c_ROWOFF[i]+j][s], u[j], acc);
        }
        sh_wg[gg][i][s] = acc;
      }
    }
    __syncthreads();
    if (tid < 96){
      int s = tid & 15, i = tid >> 4;
      float acc = sh_c[i][s];
      acc = fmaf(sh_qd[2*G][s],   sh_wg[0][i][s], acc);
      acc = fmaf(sh_qd[2*G+1][s], sh_wg[1][i][s], acc);
      int gi = i - 2*G;
      if (gi == 0 || gi == 1){
        float r = 0.f;
        #pragma unroll
        for (int j=0;j<6;j++) r = fmaf(sh_qd[j][s], sh_wg[gi][j][s], r);
        acc -= 0.5f*r;
      }
      sh_c[i][s] = acc;
    }
    __syncthreads();
  }

  // ---- V-net L1 (VALU) -> Bact
  {
    float2 bb = *reinterpret_cast<const float2*>(b1V + 2*l);
    float4 z0 = f4all(bb.x), z1 = f4all(bb.y);
    #pragma unroll
    for (int i=0;i<12;i++){
      float2 wv = *reinterpret_cast<const float2*>(W1VT + i*128 + 2*l);
      float4 a = *chunkc(sh_t, i, w);
      fma4(z0, wv.x, a); fma4(z1, wv.y, a);
    }
    float4 h0 = sp4(z0), h1 = sp4(z1);
    #pragma unroll
    for (int j=0;j<4;j++)
      stB2(Bact[0], Bact[1], 4*w+j, 2*l, (&h0.x)[j], (&h1.x)[j]);
  }
  __syncthreads();
  // ---- L2V MFMA; epilogue g2 = sig(z)*W3V -> Bact in-place
  {
    f32x4 acc0 = {0.f,0.f,0.f,0.f}, acc1 = {0.f,0.f,0.f,0.f};
    #pragma unroll
    for (int q=0;q<4;q++){
      half8_t bh = ldB(Bact[0], lane_n, q, quad);
      half8_t bl = ldB(Bact[1], lane_n, q, quad);
      acc0 = mfma3(fW2Vh[(w*4+q)*64+l],     fW2Vl[(w*4+q)*64+l],     bh, bl, acc0);
      acc1 = mfma3(fW2Vh[((w+4)*4+q)*64+l], fW2Vl[((w+4)*4+q)*64+l], bh, bl, acc1);
    }
    __syncthreads();
    float4 ba  = *reinterpret_cast<const float4*>(b2V + base0);
    float4 bb  = *reinterpret_cast<const float4*>(b2V + base1);
    float4 w3a = *reinterpret_cast<const float4*>(W3V + base0);
    float4 w3b = *reinterpret_cast<const float4*>(W3V + base1);
    float4 g2a, g2b;
    #pragma unroll
    for (int j=0;j<4;j++){
      (&g2a.x)[j] = sig_f(acc0[j] + (&ba.x)[j]) * (&w3a.x)[j];
      (&g2b.x)[j] = sig_f(acc1[j] + (&bb.x)[j]) * (&w3b.x)[j];
    }
    stB4(Bact[0], Bact[1], lane_n, base0, g2a);
    stB4(Bact[0], Bact[1], lane_n, base1, g2b);
  }
  __syncthreads();
  // ---- V bwd MFMA (A = W2V^T); epilogue: recompute s1V, g1 -> Bd[0] (hi/lo)
  {
    f32x4 acc0 = {0.f,0.f,0.f,0.f}, acc1 = {0.f,0.f,0.f,0.f};
    #pragma unroll
    for (int q=0;q<4;q++){
      half8_t bh = ldB(Bact[0], lane_n, q, quad);
      half8_t bl = ldB(Bact[1], lane_n, q, quad);
      acc0 = mfma3(fW2VTh[(w*4+q)*64+l],     fW2VTl[(w*4+q)*64+l],     bh, bl, acc0);
      acc1 = mfma3(fW2VTh[((w+4)*4+q)*64+l], fW2VTl[((w+4)*4+q)*64+l], bh, bl, acc1);
    }
    float tn[12];
    #pragma unroll
    for (int i=0;i<12;i++) tn[i] = el(sh_t, i, lane_n);
    float4 g1a, g1b;
    #pragma unroll
    for (int j=0;j<4;j++){
      int r = base0 + j;
      float z = b1V[r];
      const float* wr = W1V + r*12;
      #pragma unroll
      for (int i=0;i<12;i++) z = fmaf(wr[i], tn[i], z);
      (&g1a.x)[j] = sig_f(z) * acc0[j];
      r = base1 + j;
      z = b1V[r];
      wr = W1V + r*12;
      #pragma unroll
      for (int i=0;i<12;i++) z = fmaf(wr[i], tn[i], z);
      (&g1b.x)[j] = sig_f(z) * acc1[j];
    }
    stB4(Bd[0][0], Bd[0][1], lane_n, base0, g1a);
    stB4(Bd[0][0], Bd[0][1], lane_n, base1, g1b);
  }
  __syncthreads();
  // ---- dV/dt = W1V^T g1 via MFMA (wave 0 only; A rows 12..15 zero)
  if (w == 0){
    f32x4 acc = {0.f,0.f,0.f,0.f};
    #pragma unroll
    for (int q=0;q<4;q++){
      half8_t bh = ldB(Bd[0][0], lane_n, q, quad);
      half8_t bl = ldB(Bd[0][1], lane_n, q, quad);
      acc = mfma3(fW1Th[q*64+l], fW1Tl[q*64+l], bh, bl, acc);
    }
    int rb = quad*4;
    #pragma unroll
    for (int j=0;j<4;j++){
      int r = rb + j;
      if (r < 12) sh_dv[r][lane_n] = acc[j];
    }
  }
  __syncthreads();
  // ---- gravity
  if (tid < 96){
    int k = tid>>4, s = tid&15;
    sh_grav[k][s] = fmaf(el(sh_t,2*k,s), sh_dv[2*k+1][s],
                         -(el(sh_t,2*k+1,s)*sh_dv[2*k][s]));
  }
  __syncthreads();
  // ---- assembly + triangular solves + folded next-stage pre
  if (l < 4){
    int s = w*4 + l;
    float Lm[21];
    #pragma unroll
    for (int o=0;o<21;o++) Lm[o] = sh_y[o][s];
    float rhs[6];
    #pragma unroll
    for (int i=0;i<6;i++) rhs[i] = sh_tau[i][s] - sh_c[i][s] - sh_grav[i][s] - sh_f[i][s];
    float z[6];
    #pragma unroll
    for (int i=0;i<6;i++){
      float acc = rhs[i];
      for (int j=0;j<i;j++) acc = fmaf(-Lm[c_ROWOFF[i]+j], z[j], acc);
      z[i] = acc * __builtin_amdgcn_rcpf(Lm[c_ROWOFF[i]+i]);
    }
    float a[6];
    #pragma unroll
    for (int i=5;i>=0;i--){
      float acc = z[i];
      for (int j=i+1;j<6;j++) acc = fmaf(-Lm[c_ROWOFF[j]+i], a[j], acc);
      a[i] = acc * __builtin_amdgcn_rcpf(Lm[c_ROWOFF[i]+i]);
    }
    int b = s0 + s;
    float* kqd_out = kqd_all + stage*B6;
    #pragma unroll
    for (int i=0;i<6;i++) kqd_out[b*6+i] = a[i];

    // folded k_pre for stage+1 (this block owns the same samples next stage)
    if (stage < 3){
      const float* o = obs + b*12;
      unsigned mask = 0;
      #pragma unroll
      for (int i=0;i<6;i++){
        float q0=o[i], qd0=o[6+i];
        float q, qd;
        if (stage == 0){
          q  = q0 + 0.5f*DT*qd0;
          qd = qd0 + 0.5f*DT*a[i];
        } else if (stage == 1){
          float k1 = kqd_all[b*6+i];
          q  = q0 + 0.5f*DT*qd0 + 0.25f*DT*DT*k1;
          qd = qd0 + 0.5f*DT*a[i];
        } else {
          float k2 = kqd_all[B6 + b*6+i];
          q  = q0 + DT*qd0 + 0.5f*DT*DT*k2;
          qd = qd0 + DT*a[i];
        }
        q_cur[b*6+i]=q; qd_cur[b*6+i]=qd;
        float lo = c_LOWER[i]+0.1f, up = c_UPPER[i]-0.1f;
        if (q <= lo || q >= up) mask |= (1u<<i);
      }
      if (mask) atomicOr(viol + stage + 1, (int)mask);
    }
  }
}

// ---------------- final RK4 combine ----------------
__global__ void __launch_bounds__(256) k_final(const float* __restrict__ obs,
    const float* __restrict__ kqd, float* __restrict__ out)
{
  int b = blockIdx.x*256 + threadIdx.x;
  if (b >= BATCH) return;
  const float* o = obs + b*12;
  float* po = out + b*12;
  #pragma unroll
  for (int i=0;i<6;i++){
    float q0=o[i], qd0=o[6+i];
    float k1=kqd[b*6+i], k2=kqd[B6+b*6+i], k3=kqd[2*B6+b*6+i], k4=kqd[3*B6+b*6+i];
    float qn = q0 + DT*qd0 + (DT*DT/6.0f)*(k1+k2+k3);
    qn = fminf(fmaxf(qn, c_LOWER[i]), c_UPPER[i]);
    po[i] = qn;
    po[6+i] = qd0 + (DT/6.0f)*(k1 + 2.0f*k2 + 2.0f*k3 + k4);
  }
}

extern "C" void kernel_launch(void* const* d_in, const int* in_sizes, int n_in,
                              void* d_out, int out_size, void* d_ws, size_t ws_size,
                              hipStream_t stream) {
  const float* obs    = (const float*)d_in[0];
  const float* action = (const float*)d_in[1];
  const float* W1L = (const float*)d_in[2];  const float* b1L = (const float*)d_in[3];
  const float* W2L = (const float*)d_in[4];  const float* b2L = (const float*)d_in[5];
  const float* W3L = (const float*)d_in[6];  const float* b3L = (const float*)d_in[7];
  const float* W1V = (const float*)d_in[8];  const float* b1V = (const float*)d_in[9];
  const float* W2V = (const float*)d_in[10]; const float* b2V = (const float*)d_in[11];
  const float* W3V = (const float*)d_in[12]; // b3V unused: only grad of V needed

  float* ws = (float*)d_ws;
  _Float16* fragHi = (_Float16*)ws;            // 55296 halves
  _Float16* fragLo = fragHi + 55296;           // 55296 halves (= 55296 floats total)
  float* W1LT  = ws + 55296;                   // 1536
  float* W1VT  = W1LT + 1536;                  // 1536
  float* b3Lp  = W1VT + 1536;                  // 32
  float* q_cur  = b3Lp + 32;                   // B6
  float* qd_cur = q_cur + B6;                  // B6
  float* kqd    = qd_cur + B6;                 // 4*B6
  int*   viol   = (int*)(kqd + 4*B6);

  float* out = (float*)d_out;

  k_init<<<64,256,0,stream>>>(W1L, W2L, W3L, W1V, W2V, b3L,
                              W1LT, W1VT, b3Lp, fragHi, fragLo, viol);
  k_pre0<<<64,256,0,stream>>>(obs, q_cur, qd_cur, viol);
  for (int s=0; s<4; ++s){
    k_accel<<<1024,256,0,stream>>>(s, obs, q_cur, qd_cur, action,
        W1LT, b1L, b2L, b3Lp, W1VT, b1V, b2V, W3V, W1V,
        fragHi, fragLo, viol, kqd);
  }
  k_final<<<64,256,0,stream>>>(obs, kqd, out);
}